// Round 10
// baseline (1709.215 us; speedup 1.0000x reference)
//
#include <hip/hip_runtime.h>
#include <math.h>
#include <type_traits>

// Fused MLP head with BINARY output (per-row top-k gate + 0.2 hardlim).
// Verified architecture: bf16-split(3-product) MFMA fast pass -> logit-margin
// flags (TAU=1e-4) -> streaming fp64 repair of flagged rows -> exact gate.
// r9: GEMM1 ported to counted-vmcnt pipelined schedule (T3+T4+T5+T2-light+T1):
//  - 256x128 tile, BK=32, 8 waves, 3 LDS buffers (144 KiB) -> prefetch never
//    hits the live buffer; ONE raw s_barrier per K-tile; vmcnt never 0 in loop.
//  - W1 pre-split to global bf16 hi/lo, staged via global_load_lds w=16 with
//    source-side XOR kq-swizzle; A reg-staged (asm loads issued 1 tile early,
//    converted after counted vmcnt) with matching ds_write/read swizzle.
//  - setprio around MFMA cluster; bijective XCD block swizzle.
// ws layout fits the PROVEN 167.8MB floor: logits in d_out (in-place topk).

#define BM 128
#define BN 128
#define BK 16      // fp64 fallback K-step
#define BKF 32     // bf16 2-phase path K-step (GEMM2)

#define TAU   1.0e-4f
#define L02F -1.3862943611198906f   /* ln(0.2/0.8) */

typedef __attribute__((ext_vector_type(8))) short  bf16x8;
typedef __attribute__((ext_vector_type(8))) ushort u16x8;
typedef __attribute__((ext_vector_type(4))) float  f32x4;

__device__ inline ushort bfhi(float f)   { return (ushort)(__float_as_uint(f) >> 16); }
__device__ inline float  bfhif(float f)  { return __uint_as_float(__float_as_uint(f) & 0xFFFF0000u); }

__device__ inline void gload_lds16(const void* g, void* l) {
    __builtin_amdgcn_global_load_lds(
        (const __attribute__((address_space(1))) unsigned int*)g,
        (__attribute__((address_space(3))) unsigned int*)l, 16, 0, 0);
}

// ---------------- fp32 -> (hi, lo) bf16 split, elementwise -----------------
__global__ __launch_bounds__(256) void split_kernel(
    const float* __restrict__ src, ushort* __restrict__ hi,
    ushort* __restrict__ lo, size_t n4)
{
    size_t i = (size_t)blockIdx.x * 256 + threadIdx.x;
    size_t stride = (size_t)gridDim.x * 256;
    for (; i < n4; i += stride) {
        float4 v = ((const float4*)src)[i];
        ushort4 h, l;
        h.x = bfhi(v.x); l.x = bfhi(v.x - bfhif(v.x));
        h.y = bfhi(v.y); l.y = bfhi(v.y - bfhif(v.y));
        h.z = bfhi(v.z); l.z = bfhi(v.z - bfhif(v.z));
        h.w = bfhi(v.w); l.w = bfhi(v.w - bfhif(v.w));
        ((ushort4*)hi)[i] = h;
        ((ushort4*)lo)[i] = l;
    }
}

// ---------------- GEMM1: pipelined bf16-split MFMA (counted vmcnt) ---------
// C(split) = relu(inp @ W1^T + b1).  Fixed shape: 16384x2048x4096.
// Tile 256x128, BK=32, 512 thr (8 waves: 4m x 2n), 3 LDS bufs of 48 KiB.
__global__ __launch_bounds__(512, 2) void bgemm1_8p(
    const float* __restrict__ inp,
    const ushort* __restrict__ w1h, const ushort* __restrict__ w1l,
    const float* __restrict__ b1,
    ushort* __restrict__ Chi, ushort* __restrict__ Clo)
{
    __shared__ ushort lds[73728];   // 3 bufs x 24576 ushorts (48 KiB each)
    const int t    = threadIdx.x;
    const int lane = t & 63;
    const int wave = t >> 6;
    const int wr   = wave >> 1;     // 0..3 (64-row block)
    const int wc   = wave & 1;      // 0..1 (64-col block)
    const int l15  = lane & 15;
    const int l4   = lane >> 4;

    // bijective XCD swizzle (1024 wgs, 1024%8==0), M-fastest within XCD
    const int bid = blockIdx.x;
    const int swz = (bid & 7) * 128 + (bid >> 3);
    const int bm  = swz & 63;       // 0..63
    const int bn  = swz >> 6;       // 0..15

    // staging roles
    const int ra  = t >> 1;                  // A row 0..255
    const int kh  = t & 1;                   // A k-half (16 floats)
    const int rb  = t >> 2;                  // B row 0..127
    const int kqb = (t & 3) ^ (rb & 3);      // logical k-quad for B gload src

    const float*  Abase = inp + ((size_t)(bm * 256 + ra)) * 4096 + kh * 16;
    const ushort* Bsh   = w1h + ((size_t)(bn * 128 + rb)) * 4096 + kqb * 8;
    const ushort* Bsl   = w1l + ((size_t)(bn * 128 + rb)) * 4096 + kqb * 8;

    f32x4 acc[4][4];
    #pragma unroll
    for (int mi = 0; mi < 4; ++mi)
        #pragma unroll
        for (int ni = 0; ni < 4; ++ni)
            acc[mi][ni] = (f32x4){0.f, 0.f, 0.f, 0.f};

    // ---- helpers -----------------------------------------------------------
    auto a_write = [&](int b, const f32x4 av[4]) {
        ushort h[16], l[16];
        #pragma unroll
        for (int i = 0; i < 4; ++i) {
            #pragma unroll
            for (int j = 0; j < 4; ++j) {
                float x = av[i][j];
                h[i * 4 + j] = bfhi(x);
                l[i * 4 + j] = bfhi(x - bfhif(x));
            }
        }
        ushort* A0 = &lds[b * 24576 + ra * 32];
        #pragma unroll
        for (int j = 0; j < 2; ++j) {
            int u = (((2 * kh + j) ^ (ra & 3)) << 3);
            *(u16x8*)&A0[u]        = *(const u16x8*)&h[j * 8];
            *(u16x8*)&A0[8192 + u] = *(const u16x8*)&l[j * 8];
        }
    };
    auto w_issue = [&](int b, int kt) {
        gload_lds16(Bsh + (size_t)kt * 32, &lds[b * 24576 + 16384 + wave * 512]);
        gload_lds16(Bsl + (size_t)kt * 32, &lds[b * 24576 + 20480 + wave * 512]);
    };
    auto a_load_asm = [&](int kt, f32x4 av[4]) {
        const float* p = Abase + (size_t)kt * 32;
        asm volatile("global_load_dwordx4 %0, %1, off"           : "=v"(av[0]) : "v"(p));
        asm volatile("global_load_dwordx4 %0, %1, off offset:16" : "=v"(av[1]) : "v"(p));
        asm volatile("global_load_dwordx4 %0, %1, off offset:32" : "=v"(av[2]) : "v"(p));
        asm volatile("global_load_dwordx4 %0, %1, off offset:48" : "=v"(av[3]) : "v"(p));
    };
    auto frag_read = [&](int b, bf16x8 ah[4], bf16x8 al[4], bf16x8 bh[4], bf16x8 bl[4]) {
        const ushort* L0 = &lds[b * 24576];
        #pragma unroll
        for (int mi = 0; mi < 4; ++mi) {
            int row = wr * 64 + mi * 16 + l15;
            int o = row * 32 + ((l4 ^ (row & 3)) << 3);
            ah[mi] = *(const bf16x8*)&L0[o];
            al[mi] = *(const bf16x8*)&L0[8192 + o];
        }
        #pragma unroll
        for (int ni = 0; ni < 4; ++ni) {
            int row = wc * 64 + ni * 16 + l15;
            int o = row * 32 + ((l4 ^ (row & 3)) << 3);
            bh[ni] = *(const bf16x8*)&L0[16384 + o];
            bl[ni] = *(const bf16x8*)&L0[20480 + o];
        }
    };
    auto do_mfma = [&](bf16x8 ah[4], bf16x8 al[4], bf16x8 bh[4], bf16x8 bl[4]) {
        __builtin_amdgcn_s_setprio(1);
        #pragma unroll
        for (int mi = 0; mi < 4; ++mi)
            #pragma unroll
            for (int ni = 0; ni < 4; ++ni) {
                acc[mi][ni] = __builtin_amdgcn_mfma_f32_16x16x32_bf16(ah[mi], bh[ni], acc[mi][ni], 0, 0, 0);
                acc[mi][ni] = __builtin_amdgcn_mfma_f32_16x16x32_bf16(ah[mi], bl[ni], acc[mi][ni], 0, 0, 0);
                acc[mi][ni] = __builtin_amdgcn_mfma_f32_16x16x32_bf16(al[mi], bh[ni], acc[mi][ni], 0, 0, 0);
            }
        __builtin_amdgcn_s_setprio(0);
    };
    #define BAR_KEEP() asm volatile("s_waitcnt lgkmcnt(0)\n\ts_barrier" ::: "memory")

    // ---- prologue: tile0 fully staged (A sync, W gload); W tile1 issued ----
    {
        f32x4 av[4];
        #pragma unroll
        for (int i = 0; i < 4; ++i) av[i] = *(const f32x4*)(Abase + i * 4);
        a_write(0, av);
        w_issue(0, 0);
        w_issue(1, 1);
        asm volatile("s_waitcnt vmcnt(0)");
        BAR_KEEP();
    }

    bf16x8 ah[4], al[4], bh[4], bl[4];
    f32x4  av[4];
    const int nt = 128;  // 4096/32

    // ---- steady loop: 1 barrier/tile, vmcnt counted (never 0) --------------
    for (int kt = 0; kt < nt - 2; ++kt) {
        const int cur = kt % 3, nb1 = (kt + 1) % 3, nb2 = (kt + 2) % 3;
        frag_read(cur, ah, al, bh, bl);
        a_load_asm(kt + 1, av);                      // A for next tile (regs)
        __builtin_amdgcn_sched_barrier(0);
        w_issue(nb2, kt + 2);                        // W two tiles ahead (LDS)
        __builtin_amdgcn_sched_barrier(0);
        asm volatile("s_waitcnt vmcnt(2)");          // A(kt+1) done; W(kt+2) in flight
        asm volatile("" : "+v"(av[0]), "+v"(av[1]), "+v"(av[2]), "+v"(av[3]));
        a_write(nb1, av);
        do_mfma(ah, al, bh, bl);
        BAR_KEEP();
    }
    // ---- tail kt = nt-2 ----------------------------------------------------
    {
        const int kt = nt - 2;
        frag_read(kt % 3, ah, al, bh, bl);
        a_load_asm(kt + 1, av);
        __builtin_amdgcn_sched_barrier(0);
        asm volatile("s_waitcnt vmcnt(0)");
        asm volatile("" : "+v"(av[0]), "+v"(av[1]), "+v"(av[2]), "+v"(av[3]));
        a_write((kt + 1) % 3, av);
        do_mfma(ah, al, bh, bl);
        BAR_KEEP();
    }
    // ---- final tile --------------------------------------------------------
    frag_read((nt - 1) % 3, ah, al, bh, bl);
    do_mfma(ah, al, bh, bl);

    // ---- epilogue: relu + split-store (verified r5 mapping) ----------------
    #pragma unroll
    for (int ni = 0; ni < 4; ++ni) {
        int col = bn * 128 + wc * 64 + ni * 16 + l15;
        float bv = b1[col];
        #pragma unroll
        for (int mi = 0; mi < 4; ++mi) {
            int rowb = bm * 256 + wr * 64 + mi * 16 + l4 * 4;
            #pragma unroll
            for (int r = 0; r < 4; ++r) {
                float v = fmaxf(acc[mi][ni][r] + bv, 0.0f);
                size_t idx = (size_t)(rowb + r) * 2048 + col;
                Chi[idx] = bfhi(v);
                Clo[idx] = bfhi(v - bfhif(v));
            }
        }
    }
    #undef BAR_KEEP
}

// ---------------- bf16-split MFMA GEMM (2-phase; GEMM2 + fallbacks) --------
template<int A_PRESPLIT, int W_PRESPLIT, int OUT_MODE>
__global__ __launch_bounds__(256) void bgemm_split(
    const float*  __restrict__ A32,
    const ushort* __restrict__ Ahg, const ushort* __restrict__ Alg, int lda,
    const float*  __restrict__ W32,
    const ushort* __restrict__ Whg, const ushort* __restrict__ Wlg, int ldw,
    const float*  __restrict__ bias,
    ushort* __restrict__ Chi, ushort* __restrict__ Clo,
    float*  __restrict__ C32, int N, int K)
{
    __shared__ __align__(16) ushort Ah[BM * BKF];
    __shared__ __align__(16) ushort Al[BM * BKF];
    __shared__ __align__(16) ushort Bh[BN * BKF];
    __shared__ __align__(16) ushort Bl[BN * BKF];

    const int t    = threadIdx.x;
    const int lane = t & 63;
    const int wave = t >> 6;
    const int wr   = wave >> 1;
    const int wc   = wave & 1;
    const int l15  = lane & 15;
    const int l4   = lane >> 4;
    const size_t bm = blockIdx.x;
    const size_t bn = blockIdx.y;

    f32x4 acc[4][4];
    #pragma unroll
    for (int mi = 0; mi < 4; ++mi)
        #pragma unroll
        for (int ni = 0; ni < 4; ++ni)
            acc[mi][ni] = (f32x4){0.f, 0.f, 0.f, 0.f};

    for (int k0 = 0; k0 < K; k0 += BKF) {
        if (A_PRESPLIT) {
            #pragma unroll
            for (int i = 0; i < 2; ++i) {
                int c = t + i * 256;
                int row = c >> 2, q = c & 3;
                size_t g = (bm * BM + row) * (size_t)lda + k0 + q * 8;
                *(uint4*)&Ah[row * BKF + q * 8] = *(const uint4*)(Ahg + g);
                *(uint4*)&Al[row * BKF + q * 8] = *(const uint4*)(Alg + g);
            }
        } else {
            #pragma unroll
            for (int i = 0; i < 4; ++i) {
                int c = t + i * 256;
                int row = c >> 3, q = c & 7;
                float4 v = *(const float4*)(A32 + (bm * BM + row) * (size_t)lda + k0 + q * 4);
                ushort4 h, l;
                h.x = bfhi(v.x); l.x = bfhi(v.x - bfhif(v.x));
                h.y = bfhi(v.y); l.y = bfhi(v.y - bfhif(v.y));
                h.z = bfhi(v.z); l.z = bfhi(v.z - bfhif(v.z));
                h.w = bfhi(v.w); l.w = bfhi(v.w - bfhif(v.w));
                *(ushort4*)&Ah[row * BKF + q * 4] = h;
                *(ushort4*)&Al[row * BKF + q * 4] = l;
            }
        }
        if (W_PRESPLIT) {
            #pragma unroll
            for (int i = 0; i < 2; ++i) {
                int c = t + i * 256;
                int row = c >> 2, q = c & 3;
                size_t g = (bn * BN + row) * (size_t)ldw + k0 + q * 8;
                *(uint4*)&Bh[row * BKF + q * 8] = *(const uint4*)(Whg + g);
                *(uint4*)&Bl[row * BKF + q * 8] = *(const uint4*)(Wlg + g);
            }
        } else {
            #pragma unroll
            for (int i = 0; i < 4; ++i) {
                int c = t + i * 256;
                int row = c >> 3, q = c & 7;
                float4 v = *(const float4*)(W32 + (bn * BN + row) * (size_t)ldw + k0 + q * 4);
                ushort4 h, l;
                h.x = bfhi(v.x); l.x = bfhi(v.x - bfhif(v.x));
                h.y = bfhi(v.y); l.y = bfhi(v.y - bfhif(v.y));
                h.z = bfhi(v.z); l.z = bfhi(v.z - bfhif(v.z));
                h.w = bfhi(v.w); l.w = bfhi(v.w - bfhif(v.w));
                *(ushort4*)&Bh[row * BKF + q * 4] = h;
                *(ushort4*)&Bl[row * BKF + q * 4] = l;
            }
        }
        __syncthreads();

        bf16x8 ah[4], al[4], bh[4], bl[4];
        #pragma unroll
        for (int mi = 0; mi < 4; ++mi) {
            int r = wr * 64 + mi * 16 + l15;
            ah[mi] = *(const bf16x8*)&Ah[r * BKF + l4 * 8];
            al[mi] = *(const bf16x8*)&Al[r * BKF + l4 * 8];
        }
        #pragma unroll
        for (int ni = 0; ni < 4; ++ni) {
            int r = wc * 64 + ni * 16 + l15;
            bh[ni] = *(const bf16x8*)&Bh[r * BKF + l4 * 8];
            bl[ni] = *(const bf16x8*)&Bl[r * BKF + l4 * 8];
        }
        #pragma unroll
        for (int mi = 0; mi < 4; ++mi)
            #pragma unroll
            for (int ni = 0; ni < 4; ++ni) {
                acc[mi][ni] = __builtin_amdgcn_mfma_f32_16x16x32_bf16(ah[mi], bh[ni], acc[mi][ni], 0, 0, 0);
                acc[mi][ni] = __builtin_amdgcn_mfma_f32_16x16x32_bf16(ah[mi], bl[ni], acc[mi][ni], 0, 0, 0);
                acc[mi][ni] = __builtin_amdgcn_mfma_f32_16x16x32_bf16(al[mi], bh[ni], acc[mi][ni], 0, 0, 0);
            }
        __syncthreads();
    }

    #pragma unroll
    for (int ni = 0; ni < 4; ++ni) {
        int col = (int)bn * BN + wc * 64 + ni * 16 + l15;
        float bv = bias[col];
        #pragma unroll
        for (int mi = 0; mi < 4; ++mi) {
            int rowb = (int)bm * BM + wr * 64 + mi * 16 + l4 * 4;
            #pragma unroll
            for (int r = 0; r < 4; ++r) {
                float v = acc[mi][ni][r] + bv;
                size_t idx = (size_t)(rowb + r) * N + col;
                if (OUT_MODE == 0) {
                    v = fmaxf(v, 0.0f);
                    Chi[idx] = bfhi(v);
                    Clo[idx] = bfhi(v - bfhif(v));
                } else {
                    C32[idx] = v;
                }
            }
        }
    }
}

// ---------------- streaming fp64 repair, stage 1 (r7-verified) -------------
__global__ __launch_bounds__(256) void repair_r1(
    const float* __restrict__ inp,
    const float* __restrict__ W1, const float* __restrict__ b1,
    double* __restrict__ h64,
    const int* __restrict__ risky, const int* __restrict__ cnt, int maxr)
{
    int c = *cnt; if (c > maxr) c = maxr;
    const int by = blockIdx.y;
    if (by * 4 >= c) return;
    __shared__ float Xs[4][4096];
    const int t = threadIdx.x;

    int ridx[4];
    #pragma unroll
    for (int r = 0; r < 4; ++r) {
        int slot = by * 4 + r;
        ridx[r] = risky[slot < c ? slot : (c - 1)];
    }
    #pragma unroll
    for (int i = 0; i < 16; ++i) {
        int lin = t + i * 256;
        int r = lin >> 10, q = lin & 1023;
        *(float4*)&Xs[r][q * 4] = *(const float4*)(inp + (size_t)ridx[r] * 4096 + q * 4);
    }
    __syncthreads();

    const int n0 = blockIdx.x * 512 + t;
    const int n1 = n0 + 256;
    const float* w0 = W1 + (size_t)n0 * 4096;
    const float* w1 = W1 + (size_t)n1 * 4096;
    double acc[2][4] = {};

    for (int k = 0; k < 4096; k += 4) {
        float4 a0 = *(const float4*)(w0 + k);
        float4 a1 = *(const float4*)(w1 + k);
        float xr[4][4];
        #pragma unroll
        for (int r = 0; r < 4; ++r)
            *(float4*)&xr[r][0] = *(const float4*)&Xs[r][k];
        const float* ap0 = &a0.x;
        const float* ap1 = &a1.x;
        #pragma unroll
        for (int j = 0; j < 4; ++j) {
            double wd0 = (double)ap0[j];
            double wd1 = (double)ap1[j];
            #pragma unroll
            for (int r = 0; r < 4; ++r) {
                double xd = (double)xr[r][j];
                acc[0][r] = fma(wd0, xd, acc[0][r]);
                acc[1][r] = fma(wd1, xd, acc[1][r]);
            }
        }
    }

    double bv0 = (double)b1[n0], bv1 = (double)b1[n1];
    #pragma unroll
    for (int r = 0; r < 4; ++r) {
        int slot = by * 4 + r;
        if (slot < c) {
            h64[(size_t)slot * 2048 + n0] = fmax(acc[0][r] + bv0, 0.0);
            h64[(size_t)slot * 2048 + n1] = fmax(acc[1][r] + bv1, 0.0);
        }
    }
}

// ---------------- streaming fp64 repair, stage 2 (r7-verified) -------------
__global__ __launch_bounds__(256) void repair_r2(
    const double* __restrict__ h64,
    const float* __restrict__ W2, const float* __restrict__ b2,
    double* __restrict__ L64,
    const int* __restrict__ cnt, int maxr)
{
    int c = *cnt; if (c > maxr) c = maxr;
    const int by = blockIdx.y;
    if (by * 4 >= c) return;
    __shared__ double Xs[4][2048];
    const int t = threadIdx.x;

    #pragma unroll
    for (int i = 0; i < 16; ++i) {
        int lin = t + i * 256;
        int r = lin >> 10, q = lin & 1023;
        int slot = by * 4 + r; if (slot >= c) slot = c - 1;
        *(double2*)&Xs[r][q * 2] = *(const double2*)(h64 + (size_t)slot * 2048 + q * 2);
    }
    __syncthreads();

    const int n0 = t;
    const int n1 = t + 256;
    const float* w0 = W2 + (size_t)n0 * 2048;
    const float* w1 = W2 + (size_t)n1 * 2048;
    double acc[2][4] = {};

    for (int k = 0; k < 2048; k += 4) {
        float4 a0 = *(const float4*)(w0 + k);
        float4 a1 = *(const float4*)(w1 + k);
        double xr[4][4];
        #pragma unroll
        for (int r = 0; r < 4; ++r) {
            *(double2*)&xr[r][0] = *(const double2*)&Xs[r][k];
            *(double2*)&xr[r][2] = *(const double2*)&Xs[r][k + 2];
        }
        const float* ap0 = &a0.x;
        const float* ap1 = &a1.x;
        #pragma unroll
        for (int j = 0; j < 4; ++j) {
            double wd0 = (double)ap0[j];
            double wd1 = (double)ap1[j];
            #pragma unroll
            for (int r = 0; r < 4; ++r) {
                acc[0][r] = fma(wd0, xr[r][j], acc[0][r]);
                acc[1][r] = fma(wd1, xr[r][j], acc[1][r]);
            }
        }
    }

    double bv0 = (double)b2[n0], bv1 = (double)b2[n1];
    #pragma unroll
    for (int r = 0; r < 4; ++r) {
        int slot = by * 4 + r;
        if (slot < c) {
            L64[(size_t)slot * 512 + n0] = acc[0][r] + bv0;
            L64[(size_t)slot * 512 + n1] = acc[1][r] + bv1;
        }
    }
}

// ---------------- fp64 GEMM (r3-verified; fallback tier only) --------------
template<typename TA, int MODE>
__global__ __launch_bounds__(256, 1) void gemm64(
    const TA* __restrict__ A, int lda,
    const float* __restrict__ W, int ldw,
    const float* __restrict__ bias,
    double* __restrict__ out64, int N, int K)
{
    __shared__ double As[BK][BM + 2];
    __shared__ double Bs[BK][BN + 2];
    const int t  = threadIdx.x;
    const int tm = t >> 4;
    const int tn = t & 15;
    const size_t bm = blockIdx.x;
    const size_t bn = blockIdx.y;
    const TA*    Ab = A + bm * BM * (size_t)lda;
    const float* Wb = W + bn * BN * (size_t)ldw;

    double acc[8][8] = {};

    for (int k0 = 0; k0 < K; k0 += BK) {
        #pragma unroll
        for (int i = 0; i < 2; ++i) {
            int f   = t + i * 256;
            int row = f >> 2;
            int kc  = (f & 3) << 2;
            if constexpr (std::is_same<TA, double>::value) {
                double2 v0 = *(const double2*)(Ab + (size_t)row * lda + k0 + kc);
                double2 v1 = *(const double2*)(Ab + (size_t)row * lda + k0 + kc + 2);
                As[kc + 0][row] = v0.x; As[kc + 1][row] = v0.y;
                As[kc + 2][row] = v1.x; As[kc + 3][row] = v1.y;
            } else {
                float4 va = *(const float4*)(Ab + (size_t)row * lda + k0 + kc);
                As[kc + 0][row] = (double)va.x; As[kc + 1][row] = (double)va.y;
                As[kc + 2][row] = (double)va.z; As[kc + 3][row] = (double)va.w;
            }
            float4 vb = *(const float4*)(Wb + (size_t)row * ldw + k0 + kc);
            Bs[kc + 0][row] = (double)vb.x; Bs[kc + 1][row] = (double)vb.y;
            Bs[kc + 2][row] = (double)vb.z; Bs[kc + 3][row] = (double)vb.w;
        }
        __syncthreads();
        #pragma unroll
        for (int k = 0; k < BK; ++k) {
            double a[8], b[8];
            #pragma unroll
            for (int i = 0; i < 4; ++i) {
                *(double2*)&a[i * 2] = *(const double2*)&As[k][tm * 8 + i * 2];
                *(double2*)&b[i * 2] = *(const double2*)&Bs[k][tn * 8 + i * 2];
            }
            #pragma unroll
            for (int i = 0; i < 8; ++i)
                #pragma unroll
                for (int j = 0; j < 8; ++j)
                    acc[i][j] = fma(a[i], b[j], acc[i][j]);
        }
        __syncthreads();
    }

    double bv[8];
    if (MODE != 2) {
        #pragma unroll
        for (int j = 0; j < 8; ++j) bv[j] = (double)bias[bn * BN + tn * 8 + j];
    }

    #pragma unroll
    for (int i = 0; i < 8; ++i) {
        size_t row  = bm * BM + (size_t)tm * 8 + i;
        size_t base = row * (size_t)N + bn * BN + tn * 8;
        #pragma unroll
        for (int j = 0; j < 8; ++j) {
            double v = acc[i][j];
            if (MODE == 0) out64[base + j] = fmax(v + bv[j], 0.0);
            if (MODE == 1) out64[base + j] = v + bv[j];
            if (MODE == 2) out64[base + j] += v;
        }
    }
}

__global__ void init_repair(int* risky, int* cnt, int maxr)
{
    int i = blockIdx.x * 256 + threadIdx.x;
    if (i == 0) *cnt = 0;
    if (i < maxr) risky[i] = 0;
}

// ---------------- fp32 top-k + margin flag + gate (in-place safe) ----------
__global__ __launch_bounds__(256) void margin_topk32(
    const float* L, float* O, int ncols,
    const int* __restrict__ kp, int* __restrict__ risky, int* __restrict__ cnt,
    int maxr)
{
    const int wave = threadIdx.x >> 6;
    const int lane = threadIdx.x & 63;
    const int k = *kp;
    const size_t row = (size_t)blockIdx.x * 4 + wave;
    const float* Lr = L + row * (size_t)ncols;

    float v[8];
    *(float4*)&v[0] = *(const float4*)(Lr + lane * 8);
    *(float4*)&v[4] = *(const float4*)(Lr + lane * 8 + 4);
    float w[8];
    #pragma unroll
    for (int j = 0; j < 8; ++j) w[j] = v[j];

    float kth = -3.0e38f, minD = 3.0e38f;
    for (int it = 0; it < k; ++it) {
        float mv = w[0]; int mj = 0;
        #pragma unroll
        for (int j = 1; j < 8; ++j)
            if (w[j] > mv) { mv = w[j]; mj = j; }
        int mi = lane * 8 + mj;
        #pragma unroll
        for (int off = 32; off; off >>= 1) {
            float ov = __shfl_xor(mv, off);
            int   oi = __shfl_xor(mi, off);
            if (ov > mv || (ov == mv && oi < mi)) { mv = ov; mi = oi; }
        }
        kth = mv;
        minD = fminf(minD, fabsf(mv - L02F));
        if ((mi >> 3) == lane) w[mi & 7] = -3.0e38f;
    }
    float nv = w[0];
    #pragma unroll
    for (int j = 1; j < 8; ++j) nv = fmaxf(nv, w[j]);
    #pragma unroll
    for (int off = 32; off; off >>= 1) nv = fmaxf(nv, __shfl_xor(nv, off));

    bool risk = ((kth - nv) < 2.0f * TAU) || (minD < TAU);
    if (risk && lane == 0) {
        int p = atomicAdd(cnt, 1);
        if (p < maxr) risky[p] = (int)row;
    }

    float o[8];
    #pragma unroll
    for (int j = 0; j < 8; ++j)
        o[j] = (v[j] >= kth && v[j] > L02F) ? 1.0f : 0.0f;
    float* Op = O + row * (size_t)ncols + lane * 8;
    *(float4*)&Op[0] = *(const float4*)&o[0];
    *(float4*)&Op[4] = *(const float4*)&o[4];
}

// ---------------- fp64 top-k (r3-verified), direct or gathered -------------
__global__ __launch_bounds__(256) void topk64_kernel(
    const double* __restrict__ L, float* __restrict__ O, int ncols,
    const int* __restrict__ kp,
    const int* __restrict__ risky, const int* __restrict__ cnt, int maxr)
{
    const int wave = threadIdx.x >> 6;
    const int lane = threadIdx.x & 63;
    const int k = *kp;
    size_t pos = (size_t)blockIdx.x * 4 + wave;
    size_t row = pos;
    if (cnt) {
        int c = *cnt; if (c > maxr) c = maxr;
        if ((int)pos >= c) return;
        row = (size_t)risky[pos];
    }
    const double* Lr = L + pos * (size_t)ncols;

    double v[8];
    #pragma unroll
    for (int j = 0; j < 8; ++j) {
        double l = Lr[lane * 8 + j];
        v[j] = 1.0 / (1.0 + exp(-l));
    }
    double w[8];
    #pragma unroll
    for (int j = 0; j < 8; ++j) w[j] = v[j];

    double kth = -1.0e300;
    for (int it = 0; it < k; ++it) {
        double mv = w[0]; int mj = 0;
        #pragma unroll
        for (int j = 1; j < 8; ++j)
            if (w[j] > mv) { mv = w[j]; mj = j; }
        int mi = lane * 8 + mj;
        #pragma unroll
        for (int off = 32; off; off >>= 1) {
            double ov = __shfl_xor(mv, off);
            int    oi = __shfl_xor(mi, off);
            if (ov > mv || (ov == mv && oi < mi)) { mv = ov; mi = oi; }
        }
        kth = mv;
        if ((mi >> 3) == lane) w[mi & 7] = -1.0e300;
    }

    float o[8];
    #pragma unroll
    for (int j = 0; j < 8; ++j)
        o[j] = (v[j] >= kth && v[j] > 0.2) ? 1.0f : 0.0f;
    float* Op = O + row * (size_t)ncols + lane * 8;
    *(float4*)&Op[0] = *(const float4*)&o[0];
    *(float4*)&Op[4] = *(const float4*)&o[4];
}

extern "C" void kernel_launch(void* const* d_in, const int* in_sizes, int n_in,
                              void* d_out, int out_size, void* d_ws, size_t ws_size,
                              hipStream_t stream) {
    const float* inp = (const float*)d_in[0];
    const float* W1  = (const float*)d_in[1];
    const float* b1  = (const float*)d_in[2];
    const float* W2  = (const float*)d_in[3];
    const float* b2  = (const float*)d_in[4];
    const int*   kp  = (const int*)d_in[5];

    const int H = in_sizes[2];              // 2048
    const int F = in_sizes[4];              // 512
    const int D = in_sizes[1] / H;          // 4096
    const int B = in_sizes[0] / D;          // 16384
    float* out = (float*)d_out;

    const int MAXR = 8192;
    const size_t szHpair = (size_t)B * H * 4;        // 128 MiB (hi+lo)
    const size_t szW1p   = (size_t)H * D * 4;        // 32 MiB (hi+lo)
    const size_t needMain = szHpair + szW1p + (size_t)MAXR * 4 + 256;  // == r4-proven
    const bool shapeOK = (D == 4096 && H == 2048 && F == 512 && B == 16384);

    if (shapeOK && ws_size >= needMain) {
        ushort* h_hi  = (ushort*)d_ws;                        // [0, 64Mi)
        ushort* h_lo  = h_hi + (size_t)B * H;                 // [64Mi, 128Mi)
        ushort* w1h   = (ushort*)((char*)d_ws + szHpair);     // [128Mi, 144Mi)
        ushort* w1l   = w1h + (size_t)H * D;                  // [144Mi, 160Mi)
        int*    risky = (int*)((char*)d_ws + szHpair + szW1p);
        int*    cnt   = risky + MAXR;
        double* h64   = (double*)d_ws;                        // repair: aliases h pair
        double* L64   = (double*)((char*)d_ws + szHpair);     // repair: aliases W1 pair
        float*  l32   = out;                                  // logits in d_out

        init_repair<<<(MAXR + 255) / 256, 256, 0, stream>>>(risky, cnt, MAXR);
        split_kernel<<<2048, 256, 0, stream>>>(W1, w1h, w1l, (size_t)H * D / 4);
        bgemm1_8p<<<1024, 512, 0, stream>>>(inp, w1h, w1l, b1, h_hi, h_lo);
        bgemm_split<1, 0, 1><<<dim3(B / BM, F / BN), 256, 0, stream>>>(
            nullptr, h_hi, h_lo, H, W2, nullptr, nullptr, H, b2,
            nullptr, nullptr, l32, F, H);
        margin_topk32<<<B / 4, 256, 0, stream>>>(l32, out, F, kp, risky, cnt, MAXR);
        repair_r1<<<dim3(4, MAXR / 4), 256, 0, stream>>>(
            inp, W1, b1, h64, risky, cnt, MAXR);
        repair_r2<<<dim3(1, MAXR / 4), 256, 0, stream>>>(
            h64, W2, b2, L64, cnt, MAXR);
        topk64_kernel<<<MAXR / 4, 256, 0, stream>>>(L64, out, F, kp, risky, cnt, MAXR);
    } else {
        // Fallback: full-fp64 chunked pipeline (verified r3).
        int Hc = H, Bc = 0;
        for (;;) {
            size_t perRow = (size_t)F * 8 + (size_t)Hc * 8;
            Bc = (int)((ws_size / perRow) / BM) * BM;
            if (Bc >= BM || Hc <= BM) break;
            Hc >>= 1;
        }
        if (Bc < BM) Bc = BM;
        if (Bc > B)  Bc = B;
        double* L   = (double*)d_ws;
        double* h64 = L + (size_t)Bc * F;

        for (int b0 = 0; b0 < B; b0 += Bc) {
            int bc = (B - b0 < Bc) ? (B - b0) : Bc;
            for (int h0 = 0; h0 < H; h0 += Hc) {
                int hc = (H - h0 < Hc) ? (H - h0) : Hc;
                gemm64<float, 0><<<dim3(bc / BM, hc / BN), 256, 0, stream>>>(
                    inp + (size_t)b0 * D, D, W1 + (size_t)h0 * D, D, b1 + h0,
                    h64, hc, D);
                if (h0 == 0)
                    gemm64<double, 1><<<dim3(bc / BM, F / BN), 256, 0, stream>>>(
                        h64, hc, W2 + h0, H, b2, L, F, hc);
                else
                    gemm64<double, 2><<<dim3(bc / BM, F / BN), 256, 0, stream>>>(
                        h64, hc, W2 + h0, H, b2, L, F, hc);
            }
            topk64_kernel<<<bc / 4, 256, 0, stream>>>(
                L, out + (size_t)b0 * F, F, kp, nullptr, nullptr, 0);
        }
    }
}

// Round 11
// 1420.517 us; speedup vs baseline: 1.2032x; 1.2032x over previous
//
#include <hip/hip_runtime.h>
#include <math.h>
#include <type_traits>

// Fused MLP head with BINARY output (per-row top-k gate + 0.2 hardlim).
// Verified architecture: bf16-split(3-product) MFMA fast pass -> logit-margin
// flags (TAU=1e-4) -> streaming fp64 repair of flagged rows -> exact gate.
// r10: fix r9's two schedule bugs:
//  (1) A-loads now double-reg-buffered: issue A(kt+2) at tile kt, consume at
//      kt+1 after ONE mid-tile vmcnt(6) (retires A(kt+1)+W(kt+1), keeps 6 in
//      flight). No wait ever targets a same-tile load -> full tile of latency
//      hiding for BOTH operands. Explicitly named ping-pong reg sets (rule 20).
//  (2) XCD mapping flipped: bm = xcd*8 + j>>4, bn = j&15 -> each XCD owns a
//      contiguous 32MiB A-slice (8 slices = L3); A fetched ~once from HBM
//      (r9: 2.1GB re-fetch from bm-fastest ordering).
//  (3) W2 pre-split (+4MiB ws; ws>=204MB proven r8) for GEMM2.

#define BM 128
#define BN 128
#define BK 16      // fp64 fallback K-step
#define BKF 32     // bf16 2-phase path K-step (GEMM2)

#define TAU   1.0e-4f
#define L02F -1.3862943611198906f   /* ln(0.2/0.8) */

typedef __attribute__((ext_vector_type(8))) short  bf16x8;
typedef __attribute__((ext_vector_type(8))) ushort u16x8;
typedef __attribute__((ext_vector_type(4))) float  f32x4;

__device__ inline ushort bfhi(float f)   { return (ushort)(__float_as_uint(f) >> 16); }
__device__ inline float  bfhif(float f)  { return __uint_as_float(__float_as_uint(f) & 0xFFFF0000u); }

__device__ inline void gload_lds16(const void* g, void* l) {
    __builtin_amdgcn_global_load_lds(
        (const __attribute__((address_space(1))) unsigned int*)g,
        (__attribute__((address_space(3))) unsigned int*)l, 16, 0, 0);
}

// ---------------- fp32 -> (hi, lo) bf16 split, elementwise -----------------
__global__ __launch_bounds__(256) void split_kernel(
    const float* __restrict__ src, ushort* __restrict__ hi,
    ushort* __restrict__ lo, size_t n4)
{
    size_t i = (size_t)blockIdx.x * 256 + threadIdx.x;
    size_t stride = (size_t)gridDim.x * 256;
    for (; i < n4; i += stride) {
        float4 v = ((const float4*)src)[i];
        ushort4 h, l;
        h.x = bfhi(v.x); l.x = bfhi(v.x - bfhif(v.x));
        h.y = bfhi(v.y); l.y = bfhi(v.y - bfhif(v.y));
        h.z = bfhi(v.z); l.z = bfhi(v.z - bfhif(v.z));
        h.w = bfhi(v.w); l.w = bfhi(v.w - bfhif(v.w));
        ((ushort4*)hi)[i] = h;
        ((ushort4*)lo)[i] = l;
    }
}

// ---------------- GEMM1: pipelined bf16-split MFMA (counted vmcnt) ---------
// C(split) = relu(inp @ W1^T + b1).  Fixed shape: 16384x2048x4096.
// Tile 256x128, BK=32, 512 thr (8 waves: 4m x 2n), 3 LDS bufs of 48 KiB.
__global__ __launch_bounds__(512, 2) void bgemm1_8p(
    const float* __restrict__ inp,
    const ushort* __restrict__ w1h, const ushort* __restrict__ w1l,
    const float* __restrict__ b1,
    ushort* __restrict__ Chi, ushort* __restrict__ Clo)
{
    __shared__ ushort lds[73728];   // 3 bufs x 24576 ushorts (48 KiB each)
    const int t    = threadIdx.x;
    const int lane = t & 63;
    const int wave = t >> 6;
    const int wr   = wave >> 1;     // 0..3 (64-row block)
    const int wc   = wave & 1;      // 0..1 (64-col block)
    const int l15  = lane & 15;
    const int l4   = lane >> 4;

    // XCD mapping: each XCD owns contiguous 8 bm x all 16 bn; bn fastest.
    const int bid = blockIdx.x;
    const int xcd = bid & 7;
    const int j   = bid >> 3;       // 0..127
    const int bm  = xcd * 8 + (j >> 4);   // 0..63
    const int bn  = j & 15;               // 0..15

    // staging roles
    const int ra  = t >> 1;                  // A row 0..255
    const int kh  = t & 1;                   // A k-half (16 floats)
    const int rb  = t >> 2;                  // B row 0..127
    const int kqb = (t & 3) ^ (rb & 3);      // logical k-quad for B gload src

    const float*  Abase = inp + ((size_t)(bm * 256 + ra)) * 4096 + kh * 16;
    const ushort* Bsh   = w1h + ((size_t)(bn * 128 + rb)) * 4096 + kqb * 8;
    const ushort* Bsl   = w1l + ((size_t)(bn * 128 + rb)) * 4096 + kqb * 8;

    f32x4 acc[4][4];
    #pragma unroll
    for (int mi = 0; mi < 4; ++mi)
        #pragma unroll
        for (int ni = 0; ni < 4; ++ni)
            acc[mi][ni] = (f32x4){0.f, 0.f, 0.f, 0.f};

    // ---- helpers -----------------------------------------------------------
    auto a_write = [&](int b, const f32x4 av[4]) {
        ushort h[16], l[16];
        #pragma unroll
        for (int i = 0; i < 4; ++i) {
            #pragma unroll
            for (int jj = 0; jj < 4; ++jj) {
                float x = av[i][jj];
                h[i * 4 + jj] = bfhi(x);
                l[i * 4 + jj] = bfhi(x - bfhif(x));
            }
        }
        ushort* A0 = &lds[b * 24576 + ra * 32];
        #pragma unroll
        for (int jj = 0; jj < 2; ++jj) {
            int u = (((2 * kh + jj) ^ (ra & 3)) << 3);
            *(u16x8*)&A0[u]        = *(const u16x8*)&h[jj * 8];
            *(u16x8*)&A0[8192 + u] = *(const u16x8*)&l[jj * 8];
        }
    };
    auto w_issue = [&](int b, int kt) {
        gload_lds16(Bsh + (size_t)kt * 32, &lds[b * 24576 + 16384 + wave * 512]);
        gload_lds16(Bsl + (size_t)kt * 32, &lds[b * 24576 + 20480 + wave * 512]);
    };
    auto a_load_asm = [&](int kt, f32x4 av[4]) {
        const float* p = Abase + (size_t)kt * 32;
        asm volatile("global_load_dwordx4 %0, %1, off"           : "=v"(av[0]) : "v"(p));
        asm volatile("global_load_dwordx4 %0, %1, off offset:16" : "=v"(av[1]) : "v"(p));
        asm volatile("global_load_dwordx4 %0, %1, off offset:32" : "=v"(av[2]) : "v"(p));
        asm volatile("global_load_dwordx4 %0, %1, off offset:48" : "=v"(av[3]) : "v"(p));
    };
    auto frag_read = [&](int b, bf16x8 ah[4], bf16x8 al[4], bf16x8 bh[4], bf16x8 bl[4]) {
        const ushort* L0 = &lds[b * 24576];
        #pragma unroll
        for (int mi = 0; mi < 4; ++mi) {
            int row = wr * 64 + mi * 16 + l15;
            int o = row * 32 + ((l4 ^ (row & 3)) << 3);
            ah[mi] = *(const bf16x8*)&L0[o];
            al[mi] = *(const bf16x8*)&L0[8192 + o];
        }
        #pragma unroll
        for (int ni = 0; ni < 4; ++ni) {
            int row = wc * 64 + ni * 16 + l15;
            int o = row * 32 + ((l4 ^ (row & 3)) << 3);
            bh[ni] = *(const bf16x8*)&L0[16384 + o];
            bl[ni] = *(const bf16x8*)&L0[20480 + o];
        }
    };
    auto do_mfma = [&](bf16x8 ah[4], bf16x8 al[4], bf16x8 bh[4], bf16x8 bl[4]) {
        __builtin_amdgcn_s_setprio(1);
        #pragma unroll
        for (int mi = 0; mi < 4; ++mi)
            #pragma unroll
            for (int ni = 0; ni < 4; ++ni) {
                acc[mi][ni] = __builtin_amdgcn_mfma_f32_16x16x32_bf16(ah[mi], bh[ni], acc[mi][ni], 0, 0, 0);
                acc[mi][ni] = __builtin_amdgcn_mfma_f32_16x16x32_bf16(ah[mi], bl[ni], acc[mi][ni], 0, 0, 0);
                acc[mi][ni] = __builtin_amdgcn_mfma_f32_16x16x32_bf16(al[mi], bh[ni], acc[mi][ni], 0, 0, 0);
            }
        __builtin_amdgcn_s_setprio(0);
    };
    #define BAR_KEEP() asm volatile("s_waitcnt lgkmcnt(0)\n\ts_barrier" ::: "memory")

    f32x4 avA[4], avB[4];

    // ---- prologue ----------------------------------------------------------
    // A(0) sync-load + write; W(0),W(1) gload; A(1)->avA.
    // vmcnt(6) completes W(0) only; leaves {A(1)x4, W(1)x2} in flight.
    {
        f32x4 a0[4];
        #pragma unroll
        for (int i = 0; i < 4; ++i) a0[i] = *(const f32x4*)(Abase + i * 4);
        a_write(0, a0);
        w_issue(0, 0);
        a_load_asm(1, avA);
        __builtin_amdgcn_sched_barrier(0);
        w_issue(1, 1);
        __builtin_amdgcn_sched_barrier(0);
        asm volatile("s_waitcnt vmcnt(6)");
        BAR_KEEP();
    }

    const int nt = 128;  // 4096/32

    // Tile body: consume holds A(kt+1) (issued tile kt-1), produce <- A(kt+2).
    // Invariant at entry: outstanding = {A(kt+1)x4, W(kt+1)x2}.
    auto tile_body = [&](int kt, f32x4 (&cons)[4], f32x4 (&prod)[4]) {
        const int cur = kt % 3, nb1 = (kt + 1) % 3, nb2 = (kt + 2) % 3;
        bf16x8 ah[4], al[4], bh[4], bl[4];
        frag_read(cur, ah, al, bh, bl);
        a_load_asm(kt + 2, prod);
        __builtin_amdgcn_sched_barrier(0);
        w_issue(nb2, kt + 2);
        __builtin_amdgcn_sched_barrier(0);
        asm volatile("s_waitcnt vmcnt(6)");   // retire A(kt+1), W(kt+1)
        asm volatile("" : "+v"(cons[0]), "+v"(cons[1]), "+v"(cons[2]), "+v"(cons[3]));
        __builtin_amdgcn_sched_barrier(0);
        a_write(nb1, cons);
        do_mfma(ah, al, bh, bl);
        BAR_KEEP();
    };

    // ---- steady loop: 126 tiles, unrolled x2 for reg ping-pong -------------
    for (int kt = 0; kt < nt - 2; kt += 2) {
        tile_body(kt,     avA, avB);
        tile_body(kt + 1, avB, avA);
    }
    // ---- tail kt = 126: consume avA = A(127); drain everything -------------
    {
        const int kt = nt - 2;
        bf16x8 ah[4], al[4], bh[4], bl[4];
        frag_read(kt % 3, ah, al, bh, bl);
        asm volatile("s_waitcnt vmcnt(0)");
        asm volatile("" : "+v"(avA[0]), "+v"(avA[1]), "+v"(avA[2]), "+v"(avA[3]));
        __builtin_amdgcn_sched_barrier(0);
        a_write((kt + 1) % 3, avA);
        do_mfma(ah, al, bh, bl);
        BAR_KEEP();
    }
    // ---- final tile --------------------------------------------------------
    {
        bf16x8 ah[4], al[4], bh[4], bl[4];
        frag_read((nt - 1) % 3, ah, al, bh, bl);
        do_mfma(ah, al, bh, bl);
    }

    // ---- epilogue: relu + split-store (verified r5 mapping) ----------------
    #pragma unroll
    for (int ni = 0; ni < 4; ++ni) {
        int col = bn * 128 + wc * 64 + ni * 16 + l15;
        float bv = b1[col];
        #pragma unroll
        for (int mi = 0; mi < 4; ++mi) {
            int rowb = bm * 256 + wr * 64 + mi * 16 + l4 * 4;
            #pragma unroll
            for (int r = 0; r < 4; ++r) {
                float v = fmaxf(acc[mi][ni][r] + bv, 0.0f);
                size_t idx = (size_t)(rowb + r) * 2048 + col;
                Chi[idx] = bfhi(v);
                Clo[idx] = bfhi(v - bfhif(v));
            }
        }
    }
    #undef BAR_KEEP
}

// ---------------- bf16-split MFMA GEMM (2-phase; GEMM2 + fallbacks) --------
template<int A_PRESPLIT, int W_PRESPLIT, int OUT_MODE>
__global__ __launch_bounds__(256) void bgemm_split(
    const float*  __restrict__ A32,
    const ushort* __restrict__ Ahg, const ushort* __restrict__ Alg, int lda,
    const float*  __restrict__ W32,
    const ushort* __restrict__ Whg, const ushort* __restrict__ Wlg, int ldw,
    const float*  __restrict__ bias,
    ushort* __restrict__ Chi, ushort* __restrict__ Clo,
    float*  __restrict__ C32, int N, int K)
{
    __shared__ __align__(16) ushort Ah[BM * BKF];
    __shared__ __align__(16) ushort Al[BM * BKF];
    __shared__ __align__(16) ushort Bh[BN * BKF];
    __shared__ __align__(16) ushort Bl[BN * BKF];

    const int t    = threadIdx.x;
    const int lane = t & 63;
    const int wave = t >> 6;
    const int wr   = wave >> 1;
    const int wc   = wave & 1;
    const int l15  = lane & 15;
    const int l4   = lane >> 4;
    const size_t bm = blockIdx.x;
    const size_t bn = blockIdx.y;

    f32x4 acc[4][4];
    #pragma unroll
    for (int mi = 0; mi < 4; ++mi)
        #pragma unroll
        for (int ni = 0; ni < 4; ++ni)
            acc[mi][ni] = (f32x4){0.f, 0.f, 0.f, 0.f};

    for (int k0 = 0; k0 < K; k0 += BKF) {
        if (A_PRESPLIT) {
            #pragma unroll
            for (int i = 0; i < 2; ++i) {
                int c = t + i * 256;
                int row = c >> 2, q = c & 3;
                size_t g = (bm * BM + row) * (size_t)lda + k0 + q * 8;
                *(uint4*)&Ah[row * BKF + q * 8] = *(const uint4*)(Ahg + g);
                *(uint4*)&Al[row * BKF + q * 8] = *(const uint4*)(Alg + g);
            }
        } else {
            #pragma unroll
            for (int i = 0; i < 4; ++i) {
                int c = t + i * 256;
                int row = c >> 3, q = c & 7;
                float4 v = *(const float4*)(A32 + (bm * BM + row) * (size_t)lda + k0 + q * 4);
                ushort4 h, l;
                h.x = bfhi(v.x); l.x = bfhi(v.x - bfhif(v.x));
                h.y = bfhi(v.y); l.y = bfhi(v.y - bfhif(v.y));
                h.z = bfhi(v.z); l.z = bfhi(v.z - bfhif(v.z));
                h.w = bfhi(v.w); l.w = bfhi(v.w - bfhif(v.w));
                *(ushort4*)&Ah[row * BKF + q * 4] = h;
                *(ushort4*)&Al[row * BKF + q * 4] = l;
            }
        }
        if (W_PRESPLIT) {
            #pragma unroll
            for (int i = 0; i < 2; ++i) {
                int c = t + i * 256;
                int row = c >> 2, q = c & 3;
                size_t g = (bn * BN + row) * (size_t)ldw + k0 + q * 8;
                *(uint4*)&Bh[row * BKF + q * 8] = *(const uint4*)(Whg + g);
                *(uint4*)&Bl[row * BKF + q * 8] = *(const uint4*)(Wlg + g);
            }
        } else {
            #pragma unroll
            for (int i = 0; i < 4; ++i) {
                int c = t + i * 256;
                int row = c >> 3, q = c & 7;
                float4 v = *(const float4*)(W32 + (bn * BN + row) * (size_t)ldw + k0 + q * 4);
                ushort4 h, l;
                h.x = bfhi(v.x); l.x = bfhi(v.x - bfhif(v.x));
                h.y = bfhi(v.y); l.y = bfhi(v.y - bfhif(v.y));
                h.z = bfhi(v.z); l.z = bfhi(v.z - bfhif(v.z));
                h.w = bfhi(v.w); l.w = bfhi(v.w - bfhif(v.w));
                *(ushort4*)&Bh[row * BKF + q * 4] = h;
                *(ushort4*)&Bl[row * BKF + q * 4] = l;
            }
        }
        __syncthreads();

        bf16x8 ah[4], al[4], bh[4], bl[4];
        #pragma unroll
        for (int mi = 0; mi < 4; ++mi) {
            int r = wr * 64 + mi * 16 + l15;
            ah[mi] = *(const bf16x8*)&Ah[r * BKF + l4 * 8];
            al[mi] = *(const bf16x8*)&Al[r * BKF + l4 * 8];
        }
        #pragma unroll
        for (int ni = 0; ni < 4; ++ni) {
            int r = wc * 64 + ni * 16 + l15;
            bh[ni] = *(const bf16x8*)&Bh[r * BKF + l4 * 8];
            bl[ni] = *(const bf16x8*)&Bl[r * BKF + l4 * 8];
        }
        #pragma unroll
        for (int mi = 0; mi < 4; ++mi)
            #pragma unroll
            for (int ni = 0; ni < 4; ++ni) {
                acc[mi][ni] = __builtin_amdgcn_mfma_f32_16x16x32_bf16(ah[mi], bh[ni], acc[mi][ni], 0, 0, 0);
                acc[mi][ni] = __builtin_amdgcn_mfma_f32_16x16x32_bf16(ah[mi], bl[ni], acc[mi][ni], 0, 0, 0);
                acc[mi][ni] = __builtin_amdgcn_mfma_f32_16x16x32_bf16(al[mi], bh[ni], acc[mi][ni], 0, 0, 0);
            }
        __syncthreads();
    }

    #pragma unroll
    for (int ni = 0; ni < 4; ++ni) {
        int col = (int)bn * BN + wc * 64 + ni * 16 + l15;
        float bv = bias[col];
        #pragma unroll
        for (int mi = 0; mi < 4; ++mi) {
            int rowb = (int)bm * BM + wr * 64 + mi * 16 + l4 * 4;
            #pragma unroll
            for (int r = 0; r < 4; ++r) {
                float v = acc[mi][ni][r] + bv;
                size_t idx = (size_t)(rowb + r) * N + col;
                if (OUT_MODE == 0) {
                    v = fmaxf(v, 0.0f);
                    Chi[idx] = bfhi(v);
                    Clo[idx] = bfhi(v - bfhif(v));
                } else {
                    C32[idx] = v;
                }
            }
        }
    }
}

// ---------------- streaming fp64 repair, stage 1 (r7-verified) -------------
__global__ __launch_bounds__(256) void repair_r1(
    const float* __restrict__ inp,
    const float* __restrict__ W1, const float* __restrict__ b1,
    double* __restrict__ h64,
    const int* __restrict__ risky, const int* __restrict__ cnt, int maxr)
{
    int c = *cnt; if (c > maxr) c = maxr;
    const int by = blockIdx.y;
    if (by * 4 >= c) return;
    __shared__ float Xs[4][4096];
    const int t = threadIdx.x;

    int ridx[4];
    #pragma unroll
    for (int r = 0; r < 4; ++r) {
        int slot = by * 4 + r;
        ridx[r] = risky[slot < c ? slot : (c - 1)];
    }
    #pragma unroll
    for (int i = 0; i < 16; ++i) {
        int lin = t + i * 256;
        int r = lin >> 10, q = lin & 1023;
        *(float4*)&Xs[r][q * 4] = *(const float4*)(inp + (size_t)ridx[r] * 4096 + q * 4);
    }
    __syncthreads();

    const int n0 = blockIdx.x * 512 + t;
    const int n1 = n0 + 256;
    const float* w0 = W1 + (size_t)n0 * 4096;
    const float* w1 = W1 + (size_t)n1 * 4096;
    double acc[2][4] = {};

    for (int k = 0; k < 4096; k += 4) {
        float4 a0 = *(const float4*)(w0 + k);
        float4 a1 = *(const float4*)(w1 + k);
        float xr[4][4];
        #pragma unroll
        for (int r = 0; r < 4; ++r)
            *(float4*)&xr[r][0] = *(const float4*)&Xs[r][k];
        const float* ap0 = &a0.x;
        const float* ap1 = &a1.x;
        #pragma unroll
        for (int j = 0; j < 4; ++j) {
            double wd0 = (double)ap0[j];
            double wd1 = (double)ap1[j];
            #pragma unroll
            for (int r = 0; r < 4; ++r) {
                double xd = (double)xr[r][j];
                acc[0][r] = fma(wd0, xd, acc[0][r]);
                acc[1][r] = fma(wd1, xd, acc[1][r]);
            }
        }
    }

    double bv0 = (double)b1[n0], bv1 = (double)b1[n1];
    #pragma unroll
    for (int r = 0; r < 4; ++r) {
        int slot = by * 4 + r;
        if (slot < c) {
            h64[(size_t)slot * 2048 + n0] = fmax(acc[0][r] + bv0, 0.0);
            h64[(size_t)slot * 2048 + n1] = fmax(acc[1][r] + bv1, 0.0);
        }
    }
}

// ---------------- streaming fp64 repair, stage 2 (r7-verified) -------------
__global__ __launch_bounds__(256) void repair_r2(
    const double* __restrict__ h64,
    const float* __restrict__ W2, const float* __restrict__ b2,
    double* __restrict__ L64,
    const int* __restrict__ cnt, int maxr)
{
    int c = *cnt; if (c > maxr) c = maxr;
    const int by = blockIdx.y;
    if (by * 4 >= c) return;
    __shared__ double Xs[4][2048];
    const int t = threadIdx.x;

    #pragma unroll
    for (int i = 0; i < 16; ++i) {
        int lin = t + i * 256;
        int r = lin >> 10, q = lin & 1023;
        int slot = by * 4 + r; if (slot >= c) slot = c - 1;
        *(double2*)&Xs[r][q * 2] = *(const double2*)(h64 + (size_t)slot * 2048 + q * 2);
    }
    __syncthreads();

    const int n0 = t;
    const int n1 = t + 256;
    const float* w0 = W2 + (size_t)n0 * 2048;
    const float* w1 = W2 + (size_t)n1 * 2048;
    double acc[2][4] = {};

    for (int k = 0; k < 2048; k += 4) {
        float4 a0 = *(const float4*)(w0 + k);
        float4 a1 = *(const float4*)(w1 + k);
        double xr[4][4];
        #pragma unroll
        for (int r = 0; r < 4; ++r) {
            *(double2*)&xr[r][0] = *(const double2*)&Xs[r][k];
            *(double2*)&xr[r][2] = *(const double2*)&Xs[r][k + 2];
        }
        const float* ap0 = &a0.x;
        const float* ap1 = &a1.x;
        #pragma unroll
        for (int j = 0; j < 4; ++j) {
            double wd0 = (double)ap0[j];
            double wd1 = (double)ap1[j];
            #pragma unroll
            for (int r = 0; r < 4; ++r) {
                acc[0][r] = fma(wd0, xr[r][j], acc[0][r]);
                acc[1][r] = fma(wd1, xr[r][j], acc[1][r]);
            }
        }
    }

    double bv0 = (double)b2[n0], bv1 = (double)b2[n1];
    #pragma unroll
    for (int r = 0; r < 4; ++r) {
        int slot = by * 4 + r;
        if (slot < c) {
            L64[(size_t)slot * 512 + n0] = acc[0][r] + bv0;
            L64[(size_t)slot * 512 + n1] = acc[1][r] + bv1;
        }
    }
}

// ---------------- fp64 GEMM (r3-verified; fallback tier only) --------------
template<typename TA, int MODE>
__global__ __launch_bounds__(256, 1) void gemm64(
    const TA* __restrict__ A, int lda,
    const float* __restrict__ W, int ldw,
    const float* __restrict__ bias,
    double* __restrict__ out64, int N, int K)
{
    __shared__ double As[BK][BM + 2];
    __shared__ double Bs[BK][BN + 2];
    const int t  = threadIdx.x;
    const int tm = t >> 4;
    const int tn = t & 15;
    const size_t bm = blockIdx.x;
    const size_t bn = blockIdx.y;
    const TA*    Ab = A + bm * BM * (size_t)lda;
    const float* Wb = W + bn * BN * (size_t)ldw;

    double acc[8][8] = {};

    for (int k0 = 0; k0 < K; k0 += BK) {
        #pragma unroll
        for (int i = 0; i < 2; ++i) {
            int f   = t + i * 256;
            int row = f >> 2;
            int kc  = (f & 3) << 2;
            if constexpr (std::is_same<TA, double>::value) {
                double2 v0 = *(const double2*)(Ab + (size_t)row * lda + k0 + kc);
                double2 v1 = *(const double2*)(Ab + (size_t)row * lda + k0 + kc + 2);
                As[kc + 0][row] = v0.x; As[kc + 1][row] = v0.y;
                As[kc + 2][row] = v1.x; As[kc + 3][row] = v1.y;
            } else {
                float4 va = *(const float4*)(Ab + (size_t)row * lda + k0 + kc);
                As[kc + 0][row] = (double)va.x; As[kc + 1][row] = (double)va.y;
                As[kc + 2][row] = (double)va.z; As[kc + 3][row] = (double)va.w;
            }
            float4 vb = *(const float4*)(Wb + (size_t)row * ldw + k0 + kc);
            Bs[kc + 0][row] = (double)vb.x; Bs[kc + 1][row] = (double)vb.y;
            Bs[kc + 2][row] = (double)vb.z; Bs[kc + 3][row] = (double)vb.w;
        }
        __syncthreads();
        #pragma unroll
        for (int k = 0; k < BK; ++k) {
            double a[8], b[8];
            #pragma unroll
            for (int i = 0; i < 4; ++i) {
                *(double2*)&a[i * 2] = *(const double2*)&As[k][tm * 8 + i * 2];
                *(double2*)&b[i * 2] = *(const double2*)&Bs[k][tn * 8 + i * 2];
            }
            #pragma unroll
            for (int i = 0; i < 8; ++i)
                #pragma unroll
                for (int j = 0; j < 8; ++j)
                    acc[i][j] = fma(a[i], b[j], acc[i][j]);
        }
        __syncthreads();
    }

    double bv[8];
    if (MODE != 2) {
        #pragma unroll
        for (int j = 0; j < 8; ++j) bv[j] = (double)bias[bn * BN + tn * 8 + j];
    }

    #pragma unroll
    for (int i = 0; i < 8; ++i) {
        size_t row  = bm * BM + (size_t)tm * 8 + i;
        size_t base = row * (size_t)N + bn * BN + tn * 8;
        #pragma unroll
        for (int j = 0; j < 8; ++j) {
            double v = acc[i][j];
            if (MODE == 0) out64[base + j] = fmax(v + bv[j], 0.0);
            if (MODE == 1) out64[base + j] = v + bv[j];
            if (MODE == 2) out64[base + j] += v;
        }
    }
}

__global__ void init_repair(int* risky, int* cnt, int maxr)
{
    int i = blockIdx.x * 256 + threadIdx.x;
    if (i == 0) *cnt = 0;
    if (i < maxr) risky[i] = 0;
}

// ---------------- fp32 top-k + margin flag + gate (in-place safe) ----------
__global__ __launch_bounds__(256) void margin_topk32(
    const float* L, float* O, int ncols,
    const int* __restrict__ kp, int* __restrict__ risky, int* __restrict__ cnt,
    int maxr)
{
    const int wave = threadIdx.x >> 6;
    const int lane = threadIdx.x & 63;
    const int k = *kp;
    const size_t row = (size_t)blockIdx.x * 4 + wave;
    const float* Lr = L + row * (size_t)ncols;

    float v[8];
    *(float4*)&v[0] = *(const float4*)(Lr + lane * 8);
    *(float4*)&v[4] = *(const float4*)(Lr + lane * 8 + 4);
    float w[8];
    #pragma unroll
    for (int j = 0; j < 8; ++j) w[j] = v[j];

    float kth = -3.0e38f, minD = 3.0e38f;
    for (int it = 0; it < k; ++it) {
        float mv = w[0]; int mj = 0;
        #pragma unroll
        for (int j = 1; j < 8; ++j)
            if (w[j] > mv) { mv = w[j]; mj = j; }
        int mi = lane * 8 + mj;
        #pragma unroll
        for (int off = 32; off; off >>= 1) {
            float ov = __shfl_xor(mv, off);
            int   oi = __shfl_xor(mi, off);
            if (ov > mv || (ov == mv && oi < mi)) { mv = ov; mi = oi; }
        }
        kth = mv;
        minD = fminf(minD, fabsf(mv - L02F));
        if ((mi >> 3) == lane) w[mi & 7] = -3.0e38f;
    }
    float nv = w[0];
    #pragma unroll
    for (int j = 1; j < 8; ++j) nv = fmaxf(nv, w[j]);
    #pragma unroll
    for (int off = 32; off; off >>= 1) nv = fmaxf(nv, __shfl_xor(nv, off));

    bool risk = ((kth - nv) < 2.0f * TAU) || (minD < TAU);
    if (risk && lane == 0) {
        int p = atomicAdd(cnt, 1);
        if (p < maxr) risky[p] = (int)row;
    }

    float o[8];
    #pragma unroll
    for (int j = 0; j < 8; ++j)
        o[j] = (v[j] >= kth && v[j] > L02F) ? 1.0f : 0.0f;
    float* Op = O + row * (size_t)ncols + lane * 8;
    *(float4*)&Op[0] = *(const float4*)&o[0];
    *(float4*)&Op[4] = *(const float4*)&o[4];
}

// ---------------- fp64 top-k (r3-verified), direct or gathered -------------
__global__ __launch_bounds__(256) void topk64_kernel(
    const double* __restrict__ L, float* __restrict__ O, int ncols,
    const int* __restrict__ kp,
    const int* __restrict__ risky, const int* __restrict__ cnt, int maxr)
{
    const int wave = threadIdx.x >> 6;
    const int lane = threadIdx.x & 63;
    const int k = *kp;
    size_t pos = (size_t)blockIdx.x * 4 + wave;
    size_t row = pos;
    if (cnt) {
        int c = *cnt; if (c > maxr) c = maxr;
        if ((int)pos >= c) return;
        row = (size_t)risky[pos];
    }
    const double* Lr = L + pos * (size_t)ncols;

    double v[8];
    #pragma unroll
    for (int j = 0; j < 8; ++j) {
        double l = Lr[lane * 8 + j];
        v[j] = 1.0 / (1.0 + exp(-l));
    }
    double w[8];
    #pragma unroll
    for (int j = 0; j < 8; ++j) w[j] = v[j];

    double kth = -1.0e300;
    for (int it = 0; it < k; ++it) {
        double mv = w[0]; int mj = 0;
        #pragma unroll
        for (int j = 1; j < 8; ++j)
            if (w[j] > mv) { mv = w[j]; mj = j; }
        int mi = lane * 8 + mj;
        #pragma unroll
        for (int off = 32; off; off >>= 1) {
            double ov = __shfl_xor(mv, off);
            int    oi = __shfl_xor(mi, off);
            if (ov > mv || (ov == mv && oi < mi)) { mv = ov; mi = oi; }
        }
        kth = mv;
        if ((mi >> 3) == lane) w[mi & 7] = -1.0e300;
    }

    float o[8];
    #pragma unroll
    for (int j = 0; j < 8; ++j)
        o[j] = (v[j] >= kth && v[j] > 0.2) ? 1.0f : 0.0f;
    float* Op = O + row * (size_t)ncols + lane * 8;
    *(float4*)&Op[0] = *(const float4*)&o[0];
    *(float4*)&Op[4] = *(const float4*)&o[4];
}

extern "C" void kernel_launch(void* const* d_in, const int* in_sizes, int n_in,
                              void* d_out, int out_size, void* d_ws, size_t ws_size,
                              hipStream_t stream) {
    const float* inp = (const float*)d_in[0];
    const float* W1  = (const float*)d_in[1];
    const float* b1  = (const float*)d_in[2];
    const float* W2  = (const float*)d_in[3];
    const float* b2  = (const float*)d_in[4];
    const int*   kp  = (const int*)d_in[5];

    const int H = in_sizes[2];              // 2048
    const int F = in_sizes[4];              // 512
    const int D = in_sizes[1] / H;          // 4096
    const int B = in_sizes[0] / D;          // 16384
    float* out = (float*)d_out;

    const int MAXR = 8192;
    const size_t szHpair = (size_t)B * H * 4;        // 128 MiB (hi+lo)
    const size_t szW1p   = (size_t)H * D * 4;        // 32 MiB (hi+lo)
    const size_t szW2p   = (size_t)F * H * 4;        // 4 MiB (hi+lo)
    const size_t needMain = szHpair + szW1p + szW2p + (size_t)MAXR * 4 + 256;
    const bool shapeOK = (D == 4096 && H == 2048 && F == 512 && B == 16384);

    if (shapeOK && ws_size >= needMain) {
        ushort* h_hi  = (ushort*)d_ws;                        // [0, 64Mi)
        ushort* h_lo  = h_hi + (size_t)B * H;                 // [64Mi, 128Mi)
        ushort* w1h   = (ushort*)((char*)d_ws + szHpair);     // [128Mi, 144Mi)
        ushort* w1l   = w1h + (size_t)H * D;                  // [144Mi, 160Mi)
        ushort* w2h   = (ushort*)((char*)d_ws + szHpair + szW1p);  // [160Mi, 162Mi)
        ushort* w2l   = w2h + (size_t)F * H;                       // [162Mi, 164Mi)
        int*    risky = (int*)((char*)d_ws + szHpair + szW1p + szW2p);
        int*    cnt   = risky + MAXR;
        double* h64   = (double*)d_ws;                        // repair: aliases h pair
        double* L64   = (double*)((char*)d_ws + szHpair);     // repair: aliases W1 pair
        float*  l32   = out;                                  // logits in d_out

        init_repair<<<(MAXR + 255) / 256, 256, 0, stream>>>(risky, cnt, MAXR);
        split_kernel<<<2048, 256, 0, stream>>>(W1, w1h, w1l, (size_t)H * D / 4);
        split_kernel<<<512, 256, 0, stream>>>(W2, w2h, w2l, (size_t)F * H / 4);
        bgemm1_8p<<<1024, 512, 0, stream>>>(inp, w1h, w1l, b1, h_hi, h_lo);
        bgemm_split<1, 1, 1><<<dim3(B / BM, F / BN), 256, 0, stream>>>(
            nullptr, h_hi, h_lo, H, nullptr, w2h, w2l, H, b2,
            nullptr, nullptr, l32, F, H);
        margin_topk32<<<B / 4, 256, 0, stream>>>(l32, out, F, kp, risky, cnt, MAXR);
        repair_r1<<<dim3(4, MAXR / 4), 256, 0, stream>>>(
            inp, W1, b1, h64, risky, cnt, MAXR);
        repair_r2<<<dim3(1, MAXR / 4), 256, 0, stream>>>(
            h64, W2, b2, L64, cnt, MAXR);
        topk64_kernel<<<MAXR / 4, 256, 0, stream>>>(L64, out, F, kp, risky, cnt, MAXR);
    } else {
        // Fallback: full-fp64 chunked pipeline (verified r3).
        int Hc = H, Bc = 0;
        for (;;) {
            size_t perRow = (size_t)F * 8 + (size_t)Hc * 8;
            Bc = (int)((ws_size / perRow) / BM) * BM;
            if (Bc >= BM || Hc <= BM) break;
            Hc >>= 1;
        }
        if (Bc < BM) Bc = BM;
        if (Bc > B)  Bc = B;
        double* L   = (double*)d_ws;
        double* h64 = L + (size_t)Bc * F;

        for (int b0 = 0; b0 < B; b0 += Bc) {
            int bc = (B - b0 < Bc) ? (B - b0) : Bc;
            for (int h0 = 0; h0 < H; h0 += Hc) {
                int hc = (H - h0 < Hc) ? (H - h0) : Hc;
                gemm64<float, 0><<<dim3(bc / BM, hc / BN), 256, 0, stream>>>(
                    inp + (size_t)b0 * D, D, W1 + (size_t)h0 * D, D, b1 + h0,
                    h64, hc, D);
                if (h0 == 0)
                    gemm64<double, 1><<<dim3(bc / BM, F / BN), 256, 0, stream>>>(
                        h64, hc, W2 + h0, H, b2, L, F, hc);
                else
                    gemm64<double, 2><<<dim3(bc / BM, F / BN), 256, 0, stream>>>(
                        h64, hc, W2 + h0, H, b2, L, F, hc);
            }
            topk64_kernel<<<bc / 4, 256, 0, stream>>>(
                L, out + (size_t)b0 * F, F, kp, nullptr, nullptr, 0);
        }
    }
}

// Round 12
// 1402.286 us; speedup vs baseline: 1.2189x; 1.0130x over previous
//
#include <hip/hip_runtime.h>
#include <math.h>
#include <type_traits>

// Fused MLP head with BINARY output (per-row top-k gate + 0.2 hardlim).
// Verified architecture: bf16-split(3-product) MFMA fast pass -> logit-margin
// flags (TAU=1e-4) -> streaming fp64 repair of flagged rows -> exact gate.
// r11:
//  (1) LDS swizzle key fixed (row&3 -> (row>>1)&3): 4-way read conflict -> 2-way
//      (free, m136). Same key on write/read/source => k-octet order unchanged,
//      numerics bit-identical.
//  (2) Tier A (ws >= ~441MB): inp pre-split to global bf16 hi/lo; GEMM1+GEMM2
//      use bgemm_glds: ALL staging via global_load_lds w=16 (6/wave/tile,
//      pre-swizzled per-lane source, linear dest), counted vmcnt(6), one
//      barrier/tile. Removes A-conversion VALU + ds_writes entirely.
//  (3) Tier B (ws >= 172MB, r10-proven): r10 reg-staged GEMM1 with fix (1);
//      GEMM2 via bgemm_glds in both tiers.

#define BM 128
#define BN 128
#define BK 16      // fp64 fallback K-step

#define TAU   1.0e-4f
#define L02F -1.3862943611198906f   /* ln(0.2/0.8) */

typedef __attribute__((ext_vector_type(8))) short  bf16x8;
typedef __attribute__((ext_vector_type(8))) ushort u16x8;
typedef __attribute__((ext_vector_type(4))) float  f32x4;

__device__ inline ushort bfhi(float f)   { return (ushort)(__float_as_uint(f) >> 16); }
__device__ inline float  bfhif(float f)  { return __uint_as_float(__float_as_uint(f) & 0xFFFF0000u); }

__device__ inline void gload_lds16(const void* g, void* l) {
    __builtin_amdgcn_global_load_lds(
        (const __attribute__((address_space(1))) unsigned int*)g,
        (__attribute__((address_space(3))) unsigned int*)l, 16, 0, 0);
}

// ---------------- fp32 -> (hi, lo) bf16 split, elementwise -----------------
__global__ __launch_bounds__(256) void split_kernel(
    const float* __restrict__ src, ushort* __restrict__ hi,
    ushort* __restrict__ lo, size_t n4)
{
    size_t i = (size_t)blockIdx.x * 256 + threadIdx.x;
    size_t stride = (size_t)gridDim.x * 256;
    for (; i < n4; i += stride) {
        float4 v = ((const float4*)src)[i];
        ushort4 h, l;
        h.x = bfhi(v.x); l.x = bfhi(v.x - bfhif(v.x));
        h.y = bfhi(v.y); l.y = bfhi(v.y - bfhif(v.y));
        h.z = bfhi(v.z); l.z = bfhi(v.z - bfhif(v.z));
        h.w = bfhi(v.w); l.w = bfhi(v.w - bfhif(v.w));
        ((ushort4*)hi)[i] = h;
        ((ushort4*)lo)[i] = l;
    }
}

// ---------------- bgemm_glds: fully gload-staged pipelined split-GEMM ------
// C = epilogue(A @ W^T + bias), A/W pre-split bf16 hi/lo, lda = ldw = K.
// Tile 256x128, BK=32, 512 thr (8 waves: 4m x 2n), 3 LDS bufs of 48 KiB.
// OUT_SPLIT 1: relu -> (Chi, Clo) pair; 0: fp32 logits -> C32.
template<int OUT_SPLIT>
__global__ __launch_bounds__(512, 2) void bgemm_glds(
    const ushort* __restrict__ aH, const ushort* __restrict__ aL,
    const ushort* __restrict__ wH, const ushort* __restrict__ wL,
    const float* __restrict__ bias,
    ushort* __restrict__ Chi, ushort* __restrict__ Clo,
    float* __restrict__ C32,
    int N, int K, int nbm, int nbn)
{
    __shared__ ushort lds[73728];   // 3 bufs x 24576 ushorts (48 KiB each)
    const int t    = threadIdx.x;
    const int lane = t & 63;
    const int wave = t >> 6;
    const int wr   = wave >> 1;     // 0..3 (64-row block)
    const int wc   = wave & 1;      // 0..1 (64-col block)
    const int l15  = lane & 15;
    const int l4   = lane >> 4;

    // XCD mapping: each XCD owns contiguous nbm/8 row-tiles; bn fastest.
    const int bid = blockIdx.x;
    const int xcd = bid & 7;
    const int j   = bid >> 3;
    const int bm  = xcd * (nbm >> 3) + j / nbn;
    const int bn  = j % nbn;

    // per-lane gload sources (pre-XOR'd k-chunk -> linear LDS dest, rule 21)
    const int c   = lane & 3;
    const int rA0 = (wave * 2 + 0) * 16 + (lane >> 2);
    const int rA1 = (wave * 2 + 1) * 16 + (lane >> 2);
    const int rB  = wave * 16 + (lane >> 2);
    const size_t offA0 = (size_t)(bm * 256 + rA0) * K + (size_t)((c ^ ((rA0 >> 1) & 3)) * 8);
    const size_t offA1 = (size_t)(bm * 256 + rA1) * K + (size_t)((c ^ ((rA1 >> 1) & 3)) * 8);
    const size_t offB  = (size_t)(bn * 128 + rB ) * K + (size_t)((c ^ ((rB  >> 1) & 3)) * 8);
    const ushort* sAh0 = aH + offA0; const ushort* sAl0 = aL + offA0;
    const ushort* sAh1 = aH + offA1; const ushort* sAl1 = aL + offA1;
    const ushort* sBh  = wH + offB;  const ushort* sBl  = wL + offB;

    f32x4 acc[4][4];
    #pragma unroll
    for (int mi = 0; mi < 4; ++mi)
        #pragma unroll
        for (int ni = 0; ni < 4; ++ni)
            acc[mi][ni] = (f32x4){0.f, 0.f, 0.f, 0.f};

    auto stage = [&](int b, int kt) {
        const size_t ko = (size_t)kt * 32;
        ushort* L0 = &lds[b * 24576];
        gload_lds16(sAh0 + ko, L0 + (wave * 2 + 0) * 512);
        gload_lds16(sAh1 + ko, L0 + (wave * 2 + 1) * 512);
        gload_lds16(sAl0 + ko, L0 + 8192 + (wave * 2 + 0) * 512);
        gload_lds16(sAl1 + ko, L0 + 8192 + (wave * 2 + 1) * 512);
        gload_lds16(sBh + ko,  L0 + 16384 + wave * 512);
        gload_lds16(sBl + ko,  L0 + 20480 + wave * 512);
    };
    auto frag_read = [&](int b, bf16x8 ah[4], bf16x8 al[4], bf16x8 bh[4], bf16x8 bl[4]) {
        const ushort* L0 = &lds[b * 24576];
        #pragma unroll
        for (int mi = 0; mi < 4; ++mi) {
            int row = wr * 64 + mi * 16 + l15;
            int o = row * 32 + ((l4 ^ ((row >> 1) & 3)) << 3);
            ah[mi] = *(const bf16x8*)&L0[o];
            al[mi] = *(const bf16x8*)&L0[8192 + o];
        }
        #pragma unroll
        for (int ni = 0; ni < 4; ++ni) {
            int row = wc * 64 + ni * 16 + l15;
            int o = row * 32 + ((l4 ^ ((row >> 1) & 3)) << 3);
            bh[ni] = *(const bf16x8*)&L0[16384 + o];
            bl[ni] = *(const bf16x8*)&L0[20480 + o];
        }
    };
    auto do_mfma = [&](bf16x8 ah[4], bf16x8 al[4], bf16x8 bh[4], bf16x8 bl[4]) {
        __builtin_amdgcn_s_setprio(1);
        #pragma unroll
        for (int mi = 0; mi < 4; ++mi)
            #pragma unroll
            for (int ni = 0; ni < 4; ++ni) {
                acc[mi][ni] = __builtin_amdgcn_mfma_f32_16x16x32_bf16(ah[mi], bh[ni], acc[mi][ni], 0, 0, 0);
                acc[mi][ni] = __builtin_amdgcn_mfma_f32_16x16x32_bf16(ah[mi], bl[ni], acc[mi][ni], 0, 0, 0);
                acc[mi][ni] = __builtin_amdgcn_mfma_f32_16x16x32_bf16(al[mi], bh[ni], acc[mi][ni], 0, 0, 0);
            }
        __builtin_amdgcn_s_setprio(0);
    };

    // ---- prologue: T(0), T(1) issued; T(0) resident -------------------------
    stage(0, 0);
    stage(1, 1);
    asm volatile("s_waitcnt vmcnt(6)");
    __builtin_amdgcn_s_barrier();

    const int nt = K / 32;
    bf16x8 ah[4], al[4], bh[4], bl[4];

    // Invariant at tile kt entry: buf[kt] resident (all waves), {T(kt+1):6} in flight.
    for (int kt = 0; kt < nt - 2; ++kt) {
        frag_read(kt % 3, ah, al, bh, bl);
        stage((kt + 2) % 3, kt + 2);
        __builtin_amdgcn_sched_barrier(0);
        do_mfma(ah, al, bh, bl);
        asm volatile("s_waitcnt vmcnt(6)");   // retire T(kt+1)
        asm volatile("s_waitcnt lgkmcnt(0)\n\ts_barrier" ::: "memory");
    }
    {   // kt = nt-2: no stage; drain T(nt-1)
        frag_read((nt - 2) % 3, ah, al, bh, bl);
        do_mfma(ah, al, bh, bl);
        asm volatile("s_waitcnt vmcnt(0)");
        asm volatile("s_waitcnt lgkmcnt(0)\n\ts_barrier" ::: "memory");
    }
    {   // final tile
        frag_read((nt - 1) % 3, ah, al, bh, bl);
        do_mfma(ah, al, bh, bl);
    }

    // ---- epilogue (verified r5 C/D mapping) --------------------------------
    #pragma unroll
    for (int ni = 0; ni < 4; ++ni) {
        int col = bn * 128 + wc * 64 + ni * 16 + l15;
        float bv = bias[col];
        #pragma unroll
        for (int mi = 0; mi < 4; ++mi) {
            int rowb = bm * 256 + wr * 64 + mi * 16 + l4 * 4;
            #pragma unroll
            for (int r = 0; r < 4; ++r) {
                float v = acc[mi][ni][r] + bv;
                size_t idx = (size_t)(rowb + r) * N + col;
                if (OUT_SPLIT) {
                    v = fmaxf(v, 0.0f);
                    Chi[idx] = bfhi(v);
                    Clo[idx] = bfhi(v - bfhif(v));
                } else {
                    C32[idx] = v;
                }
            }
        }
    }
}

// ---------------- GEMM1 Tier B: reg-staged A (r10-verified + swizzle fix) --
__global__ __launch_bounds__(512, 2) void bgemm1_8p(
    const float* __restrict__ inp,
    const ushort* __restrict__ w1h, const ushort* __restrict__ w1l,
    const float* __restrict__ b1,
    ushort* __restrict__ Chi, ushort* __restrict__ Clo)
{
    __shared__ ushort lds[73728];
    const int t    = threadIdx.x;
    const int lane = t & 63;
    const int wave = t >> 6;
    const int wr   = wave >> 1;
    const int wc   = wave & 1;
    const int l15  = lane & 15;
    const int l4   = lane >> 4;

    const int bid = blockIdx.x;
    const int xcd = bid & 7;
    const int j   = bid >> 3;
    const int bm  = xcd * 8 + (j >> 4);
    const int bn  = j & 15;

    const int ra  = t >> 1;
    const int kh  = t & 1;
    const int rb  = t >> 2;
    const int kqb = (t & 3) ^ ((rb >> 1) & 3);

    const float*  Abase = inp + ((size_t)(bm * 256 + ra)) * 4096 + kh * 16;
    const ushort* Bsh   = w1h + ((size_t)(bn * 128 + rb)) * 4096 + kqb * 8;
    const ushort* Bsl   = w1l + ((size_t)(bn * 128 + rb)) * 4096 + kqb * 8;

    f32x4 acc[4][4];
    #pragma unroll
    for (int mi = 0; mi < 4; ++mi)
        #pragma unroll
        for (int ni = 0; ni < 4; ++ni)
            acc[mi][ni] = (f32x4){0.f, 0.f, 0.f, 0.f};

    auto a_write = [&](int b, const f32x4 av[4]) {
        ushort h[16], l[16];
        #pragma unroll
        for (int i = 0; i < 4; ++i) {
            #pragma unroll
            for (int jj = 0; jj < 4; ++jj) {
                float x = av[i][jj];
                h[i * 4 + jj] = bfhi(x);
                l[i * 4 + jj] = bfhi(x - bfhif(x));
            }
        }
        ushort* A0 = &lds[b * 24576 + ra * 32];
        #pragma unroll
        for (int jj = 0; jj < 2; ++jj) {
            int u = (((2 * kh + jj) ^ ((ra >> 1) & 3)) << 3);
            *(u16x8*)&A0[u]        = *(const u16x8*)&h[jj * 8];
            *(u16x8*)&A0[8192 + u] = *(const u16x8*)&l[jj * 8];
        }
    };
    auto w_issue = [&](int b, int kt) {
        gload_lds16(Bsh + (size_t)kt * 32, &lds[b * 24576 + 16384 + wave * 512]);
        gload_lds16(Bsl + (size_t)kt * 32, &lds[b * 24576 + 20480 + wave * 512]);
    };
    auto a_load_asm = [&](int kt, f32x4 av[4]) {
        const float* p = Abase + (size_t)kt * 32;
        asm volatile("global_load_dwordx4 %0, %1, off"           : "=v"(av[0]) : "v"(p));
        asm volatile("global_load_dwordx4 %0, %1, off offset:16" : "=v"(av[1]) : "v"(p));
        asm volatile("global_load_dwordx4 %0, %1, off offset:32" : "=v"(av[2]) : "v"(p));
        asm volatile("global_load_dwordx4 %0, %1, off offset:48" : "=v"(av[3]) : "v"(p));
    };
    auto frag_read = [&](int b, bf16x8 ah[4], bf16x8 al[4], bf16x8 bh[4], bf16x8 bl[4]) {
        const ushort* L0 = &lds[b * 24576];
        #pragma unroll
        for (int mi = 0; mi < 4; ++mi) {
            int row = wr * 64 + mi * 16 + l15;
            int o = row * 32 + ((l4 ^ ((row >> 1) & 3)) << 3);
            ah[mi] = *(const bf16x8*)&L0[o];
            al[mi] = *(const bf16x8*)&L0[8192 + o];
        }
        #pragma unroll
        for (int ni = 0; ni < 4; ++ni) {
            int row = wc * 64 + ni * 16 + l15;
            int o = row * 32 + ((l4 ^ ((row >> 1) & 3)) << 3);
            bh[ni] = *(const bf16x8*)&L0[16384 + o];
            bl[ni] = *(const bf16x8*)&L0[20480 + o];
        }
    };
    auto do_mfma = [&](bf16x8 ah[4], bf16x8 al[4], bf16x8 bh[4], bf16x8 bl[4]) {
        __builtin_amdgcn_s_setprio(1);
        #pragma unroll
        for (int mi = 0; mi < 4; ++mi)
            #pragma unroll
            for (int ni = 0; ni < 4; ++ni) {
                acc[mi][ni] = __builtin_amdgcn_mfma_f32_16x16x32_bf16(ah[mi], bh[ni], acc[mi][ni], 0, 0, 0);
                acc[mi][ni] = __builtin_amdgcn_mfma_f32_16x16x32_bf16(ah[mi], bl[ni], acc[mi][ni], 0, 0, 0);
                acc[mi][ni] = __builtin_amdgcn_mfma_f32_16x16x32_bf16(al[mi], bh[ni], acc[mi][ni], 0, 0, 0);
            }
        __builtin_amdgcn_s_setprio(0);
    };
    #define BAR_KEEP() asm volatile("s_waitcnt lgkmcnt(0)\n\ts_barrier" ::: "memory")

    f32x4 avA[4], avB[4];
    {
        f32x4 a0[4];
        #pragma unroll
        for (int i = 0; i < 4; ++i) a0[i] = *(const f32x4*)(Abase + i * 4);
        a_write(0, a0);
        w_issue(0, 0);
        a_load_asm(1, avA);
        __builtin_amdgcn_sched_barrier(0);
        w_issue(1, 1);
        __builtin_amdgcn_sched_barrier(0);
        asm volatile("s_waitcnt vmcnt(6)");
        BAR_KEEP();
    }

    const int nt = 128;
    auto tile_body = [&](int kt, f32x4 (&cons)[4], f32x4 (&prod)[4]) {
        const int cur = kt % 3, nb1 = (kt + 1) % 3, nb2 = (kt + 2) % 3;
        bf16x8 ah[4], al[4], bh[4], bl[4];
        frag_read(cur, ah, al, bh, bl);
        a_load_asm(kt + 2, prod);
        __builtin_amdgcn_sched_barrier(0);
        w_issue(nb2, kt + 2);
        __builtin_amdgcn_sched_barrier(0);
        asm volatile("s_waitcnt vmcnt(6)");
        asm volatile("" : "+v"(cons[0]), "+v"(cons[1]), "+v"(cons[2]), "+v"(cons[3]));
        __builtin_amdgcn_sched_barrier(0);
        a_write(nb1, cons);
        do_mfma(ah, al, bh, bl);
        BAR_KEEP();
    };

    for (int kt = 0; kt < nt - 2; kt += 2) {
        tile_body(kt,     avA, avB);
        tile_body(kt + 1, avB, avA);
    }
    {
        const int kt = nt - 2;
        bf16x8 ah[4], al[4], bh[4], bl[4];
        frag_read(kt % 3, ah, al, bh, bl);
        asm volatile("s_waitcnt vmcnt(0)");
        asm volatile("" : "+v"(avA[0]), "+v"(avA[1]), "+v"(avA[2]), "+v"(avA[3]));
        __builtin_amdgcn_sched_barrier(0);
        a_write((kt + 1) % 3, avA);
        do_mfma(ah, al, bh, bl);
        BAR_KEEP();
    }
    {
        bf16x8 ah[4], al[4], bh[4], bl[4];
        frag_read((nt - 1) % 3, ah, al, bh, bl);
        do_mfma(ah, al, bh, bl);
    }

    #pragma unroll
    for (int ni = 0; ni < 4; ++ni) {
        int col = bn * 128 + wc * 64 + ni * 16 + l15;
        float bv = b1[col];
        #pragma unroll
        for (int mi = 0; mi < 4; ++mi) {
            int rowb = bm * 256 + wr * 64 + mi * 16 + l4 * 4;
            #pragma unroll
            for (int r = 0; r < 4; ++r) {
                float v = fmaxf(acc[mi][ni][r] + bv, 0.0f);
                size_t idx = (size_t)(rowb + r) * 2048 + col;
                Chi[idx] = bfhi(v);
                Clo[idx] = bfhi(v - bfhif(v));
            }
        }
    }
    #undef BAR_KEEP
}

// ---------------- streaming fp64 repair, stage 1 (r7-verified) -------------
__global__ __launch_bounds__(256) void repair_r1(
    const float* __restrict__ inp,
    const float* __restrict__ W1, const float* __restrict__ b1,
    double* __restrict__ h64,
    const int* __restrict__ risky, const int* __restrict__ cnt, int maxr)
{
    int c = *cnt; if (c > maxr) c = maxr;
    const int by = blockIdx.y;
    if (by * 4 >= c) return;
    __shared__ float Xs[4][4096];
    const int t = threadIdx.x;

    int ridx[4];
    #pragma unroll
    for (int r = 0; r < 4; ++r) {
        int slot = by * 4 + r;
        ridx[r] = risky[slot < c ? slot : (c - 1)];
    }
    #pragma unroll
    for (int i = 0; i < 16; ++i) {
        int lin = t + i * 256;
        int r = lin >> 10, q = lin & 1023;
        *(float4*)&Xs[r][q * 4] = *(const float4*)(inp + (size_t)ridx[r] * 4096 + q * 4);
    }
    __syncthreads();

    const int n0 = blockIdx.x * 512 + t;
    const int n1 = n0 + 256;
    const float* w0 = W1 + (size_t)n0 * 4096;
    const float* w1 = W1 + (size_t)n1 * 4096;
    double acc[2][4] = {};

    for (int k = 0; k < 4096; k += 4) {
        float4 a0 = *(const float4*)(w0 + k);
        float4 a1 = *(const float4*)(w1 + k);
        float xr[4][4];
        #pragma unroll
        for (int r = 0; r < 4; ++r)
            *(float4*)&xr[r][0] = *(const float4*)&Xs[r][k];
        const float* ap0 = &a0.x;
        const float* ap1 = &a1.x;
        #pragma unroll
        for (int j = 0; j < 4; ++j) {
            double wd0 = (double)ap0[j];
            double wd1 = (double)ap1[j];
            #pragma unroll
            for (int r = 0; r < 4; ++r) {
                double xd = (double)xr[r][j];
                acc[0][r] = fma(wd0, xd, acc[0][r]);
                acc[1][r] = fma(wd1, xd, acc[1][r]);
            }
        }
    }

    double bv0 = (double)b1[n0], bv1 = (double)b1[n1];
    #pragma unroll
    for (int r = 0; r < 4; ++r) {
        int slot = by * 4 + r;
        if (slot < c) {
            h64[(size_t)slot * 2048 + n0] = fmax(acc[0][r] + bv0, 0.0);
            h64[(size_t)slot * 2048 + n1] = fmax(acc[1][r] + bv1, 0.0);
        }
    }
}

// ---------------- streaming fp64 repair, stage 2 (r7-verified) -------------
__global__ __launch_bounds__(256) void repair_r2(
    const double* __restrict__ h64,
    const float* __restrict__ W2, const float* __restrict__ b2,
    double* __restrict__ L64,
    const int* __restrict__ cnt, int maxr)
{
    int c = *cnt; if (c > maxr) c = maxr;
    const int by = blockIdx.y;
    if (by * 4 >= c) return;
    __shared__ double Xs[4][2048];
    const int t = threadIdx.x;

    #pragma unroll
    for (int i = 0; i < 16; ++i) {
        int lin = t + i * 256;
        int r = lin >> 10, q = lin & 1023;
        int slot = by * 4 + r; if (slot >= c) slot = c - 1;
        *(double2*)&Xs[r][q * 2] = *(const double2*)(h64 + (size_t)slot * 2048 + q * 2);
    }
    __syncthreads();

    const int n0 = t;
    const int n1 = t + 256;
    const float* w0 = W2 + (size_t)n0 * 2048;
    const float* w1 = W2 + (size_t)n1 * 2048;
    double acc[2][4] = {};

    for (int k = 0; k < 2048; k += 4) {
        float4 a0 = *(const float4*)(w0 + k);
        float4 a1 = *(const float4*)(w1 + k);
        double xr[4][4];
        #pragma unroll
        for (int r = 0; r < 4; ++r) {
            *(double2*)&xr[r][0] = *(const double2*)&Xs[r][k];
            *(double2*)&xr[r][2] = *(const double2*)&Xs[r][k + 2];
        }
        const float* ap0 = &a0.x;
        const float* ap1 = &a1.x;
        #pragma unroll
        for (int j = 0; j < 4; ++j) {
            double wd0 = (double)ap0[j];
            double wd1 = (double)ap1[j];
            #pragma unroll
            for (int r = 0; r < 4; ++r) {
                acc[0][r] = fma(wd0, xr[r][j], acc[0][r]);
                acc[1][r] = fma(wd1, xr[r][j], acc[1][r]);
            }
        }
    }

    double bv0 = (double)b2[n0], bv1 = (double)b2[n1];
    #pragma unroll
    for (int r = 0; r < 4; ++r) {
        int slot = by * 4 + r;
        if (slot < c) {
            L64[(size_t)slot * 512 + n0] = acc[0][r] + bv0;
            L64[(size_t)slot * 512 + n1] = acc[1][r] + bv1;
        }
    }
}

// ---------------- fp64 GEMM (r3-verified; fallback tier only) --------------
template<typename TA, int MODE>
__global__ __launch_bounds__(256, 1) void gemm64(
    const TA* __restrict__ A, int lda,
    const float* __restrict__ W, int ldw,
    const float* __restrict__ bias,
    double* __restrict__ out64, int N, int K)
{
    __shared__ double As[BK][BM + 2];
    __shared__ double Bs[BK][BN + 2];
    const int t  = threadIdx.x;
    const int tm = t >> 4;
    const int tn = t & 15;
    const size_t bm = blockIdx.x;
    const size_t bn = blockIdx.y;
    const TA*    Ab = A + bm * BM * (size_t)lda;
    const float* Wb = W + bn * BN * (size_t)ldw;

    double acc[8][8] = {};

    for (int k0 = 0; k0 < K; k0 += BK) {
        #pragma unroll
        for (int i = 0; i < 2; ++i) {
            int f   = t + i * 256;
            int row = f >> 2;
            int kc  = (f & 3) << 2;
            if constexpr (std::is_same<TA, double>::value) {
                double2 v0 = *(const double2*)(Ab + (size_t)row * lda + k0 + kc);
                double2 v1 = *(const double2*)(Ab + (size_t)row * lda + k0 + kc + 2);
                As[kc + 0][row] = v0.x; As[kc + 1][row] = v0.y;
                As[kc + 2][row] = v1.x; As[kc + 3][row] = v1.y;
            } else {
                float4 va = *(const float4*)(Ab + (size_t)row * lda + k0 + kc);
                As[kc + 0][row] = (double)va.x; As[kc + 1][row] = (double)va.y;
                As[kc + 2][row] = (double)va.z; As[kc + 3][row] = (double)va.w;
            }
            float4 vb = *(const float4*)(Wb + (size_t)row * ldw + k0 + kc);
            Bs[kc + 0][row] = (double)vb.x; Bs[kc + 1][row] = (double)vb.y;
            Bs[kc + 2][row] = (double)vb.z; Bs[kc + 3][row] = (double)vb.w;
        }
        __syncthreads();
        #pragma unroll
        for (int k = 0; k < BK; ++k) {
            double a[8], b[8];
            #pragma unroll
            for (int i = 0; i < 4; ++i) {
                *(double2*)&a[i * 2] = *(const double2*)&As[k][tm * 8 + i * 2];
                *(double2*)&b[i * 2] = *(const double2*)&Bs[k][tn * 8 + i * 2];
            }
            #pragma unroll
            for (int i = 0; i < 8; ++i)
                #pragma unroll
                for (int j = 0; j < 8; ++j)
                    acc[i][j] = fma(a[i], b[j], acc[i][j]);
        }
        __syncthreads();
    }

    double bv[8];
    if (MODE != 2) {
        #pragma unroll
        for (int j = 0; j < 8; ++j) bv[j] = (double)bias[bn * BN + tn * 8 + j];
    }

    #pragma unroll
    for (int i = 0; i < 8; ++i) {
        size_t row  = bm * BM + (size_t)tm * 8 + i;
        size_t base = row * (size_t)N + bn * BN + tn * 8;
        #pragma unroll
        for (int j = 0; j < 8; ++j) {
            double v = acc[i][j];
            if (MODE == 0) out64[base + j] = fmax(v + bv[j], 0.0);
            if (MODE == 1) out64[base + j] = v + bv[j];
            if (MODE == 2) out64[base + j] += v;
        }
    }
}

__global__ void init_repair(int* risky, int* cnt, int maxr)
{
    int i = blockIdx.x * 256 + threadIdx.x;
    if (i == 0) *cnt = 0;
    if (i < maxr) risky[i] = 0;
}

// ---------------- fp32 top-k + margin flag + gate (in-place safe) ----------
__global__ __launch_bounds__(256) void margin_topk32(
    const float* L, float* O, int ncols,
    const int* __restrict__ kp, int* __restrict__ risky, int* __restrict__ cnt,
    int maxr)
{
    const int wave = threadIdx.x >> 6;
    const int lane = threadIdx.x & 63;
    const int k = *kp;
    const size_t row = (size_t)blockIdx.x * 4 + wave;
    const float* Lr = L + row * (size_t)ncols;

    float v[8];
    *(float4*)&v[0] = *(const float4*)(Lr + lane * 8);
    *(float4*)&v[4] = *(const float4*)(Lr + lane * 8 + 4);
    float w[8];
    #pragma unroll
    for (int j = 0; j < 8; ++j) w[j] = v[j];

    float kth = -3.0e38f, minD = 3.0e38f;
    for (int it = 0; it < k; ++it) {
        float mv = w[0]; int mj = 0;
        #pragma unroll
        for (int j = 1; j < 8; ++j)
            if (w[j] > mv) { mv = w[j]; mj = j; }
        int mi = lane * 8 + mj;
        #pragma unroll
        for (int off = 32; off; off >>= 1) {
            float ov = __shfl_xor(mv, off);
            int   oi = __shfl_xor(mi, off);
            if (ov > mv || (ov == mv && oi < mi)) { mv = ov; mi = oi; }
        }
        kth = mv;
        minD = fminf(minD, fabsf(mv - L02F));
        if ((mi >> 3) == lane) w[mi & 7] = -3.0e38f;
    }
    float nv = w[0];
    #pragma unroll
    for (int j = 1; j < 8; ++j) nv = fmaxf(nv, w[j]);
    #pragma unroll
    for (int off = 32; off; off >>= 1) nv = fmaxf(nv, __shfl_xor(nv, off));

    bool risk = ((kth - nv) < 2.0f * TAU) || (minD < TAU);
    if (risk && lane == 0) {
        int p = atomicAdd(cnt, 1);
        if (p < maxr) risky[p] = (int)row;
    }

    float o[8];
    #pragma unroll
    for (int j = 0; j < 8; ++j)
        o[j] = (v[j] >= kth && v[j] > L02F) ? 1.0f : 0.0f;
    float* Op = O + row * (size_t)ncols + lane * 8;
    *(float4*)&Op[0] = *(const float4*)&o[0];
    *(float4*)&Op[4] = *(const float4*)&o[4];
}

// ---------------- fp64 top-k (r3-verified), direct or gathered -------------
__global__ __launch_bounds__(256) void topk64_kernel(
    const double* __restrict__ L, float* __restrict__ O, int ncols,
    const int* __restrict__ kp,
    const int* __restrict__ risky, const int* __restrict__ cnt, int maxr)
{
    const int wave = threadIdx.x >> 6;
    const int lane = threadIdx.x & 63;
    const int k = *kp;
    size_t pos = (size_t)blockIdx.x * 4 + wave;
    size_t row = pos;
    if (cnt) {
        int c = *cnt; if (c > maxr) c = maxr;
        if ((int)pos >= c) return;
        row = (size_t)risky[pos];
    }
    const double* Lr = L + pos * (size_t)ncols;

    double v[8];
    #pragma unroll
    for (int j = 0; j < 8; ++j) {
        double l = Lr[lane * 8 + j];
        v[j] = 1.0 / (1.0 + exp(-l));
    }
    double w[8];
    #pragma unroll
    for (int j = 0; j < 8; ++j) w[j] = v[j];

    double kth = -1.0e300;
    for (int it = 0; it < k; ++it) {
        double mv = w[0]; int mj = 0;
        #pragma unroll
        for (int j = 1; j < 8; ++j)
            if (w[j] > mv) { mv = w[j]; mj = j; }
        int mi = lane * 8 + mj;
        #pragma unroll
        for (int off = 32; off; off >>= 1) {
            double ov = __shfl_xor(mv, off);
            int    oi = __shfl_xor(mi, off);
            if (ov > mv || (ov == mv && oi < mi)) { mv = ov; mi = oi; }
        }
        kth = mv;
        if ((mi >> 3) == lane) w[mi & 7] = -1.0e300;
    }

    float o[8];
    #pragma unroll
    for (int j = 0; j < 8; ++j)
        o[j] = (v[j] >= kth && v[j] > 0.2) ? 1.0f : 0.0f;
    float* Op = O + row * (size_t)ncols + lane * 8;
    *(float4*)&Op[0] = *(const float4*)&o[0];
    *(float4*)&Op[4] = *(const float4*)&o[4];
}

extern "C" void kernel_launch(void* const* d_in, const int* in_sizes, int n_in,
                              void* d_out, int out_size, void* d_ws, size_t ws_size,
                              hipStream_t stream) {
    const float* inp = (const float*)d_in[0];
    const float* W1  = (const float*)d_in[1];
    const float* b1  = (const float*)d_in[2];
    const float* W2  = (const float*)d_in[3];
    const float* b2  = (const float*)d_in[4];
    const int*   kp  = (const int*)d_in[5];

    const int H = in_sizes[2];              // 2048
    const int F = in_sizes[4];              // 512
    const int D = in_sizes[1] / H;          // 4096
    const int B = in_sizes[0] / D;          // 16384
    float* out = (float*)d_out;

    const int MAXR = 8192;
    const size_t szHpair = (size_t)B * H * 4;        // 128 MiB (hi+lo)
    const size_t szW1p   = (size_t)H * D * 4;        // 32 MiB
    const size_t szW2p   = (size_t)F * H * 4;        // 4 MiB
    const size_t szInpP  = (size_t)B * D * 4;        // 256 MiB
    const size_t needMain = szHpair + szW1p + szW2p + (size_t)MAXR * 4 + 256;
    const size_t needA    = needMain + szInpP;
    const bool shapeOK = (D == 4096 && H == 2048 && F == 512 && B == 16384);

    if (shapeOK && ws_size >= needMain) {
        ushort* h_hi  = (ushort*)d_ws;
        ushort* h_lo  = h_hi + (size_t)B * H;
        ushort* w1h   = (ushort*)((char*)d_ws + szHpair);
        ushort* w1l   = w1h + (size_t)H * D;
        ushort* w2h   = (ushort*)((char*)d_ws + szHpair + szW1p);
        ushort* w2l   = w2h + (size_t)F * H;
        int*    risky = (int*)((char*)d_ws + szHpair + szW1p + szW2p);
        int*    cnt   = risky + MAXR;
        double* h64   = (double*)d_ws;                        // repair: aliases h pair
        double* L64   = (double*)((char*)d_ws + szHpair);     // repair: aliases W1 pair
        float*  l32   = out;                                  // logits in d_out

        init_repair<<<(MAXR + 255) / 256, 256, 0, stream>>>(risky, cnt, MAXR);
        split_kernel<<<2048, 256, 0, stream>>>(W1, w1h, w1l, (size_t)H * D / 4);
        split_kernel<<<512, 256, 0, stream>>>(W2, w2h, w2l, (size_t)F * H / 4);

        if (ws_size >= needA) {
            // Tier A: inp pre-split; GEMM1 fully gload-staged.
            ushort* inH = (ushort*)((char*)d_ws + needMain);
            ushort* inL = inH + (size_t)B * D;
            split_kernel<<<4096, 256, 0, stream>>>(inp, inH, inL, (size_t)B * D / 4);
            bgemm_glds<1><<<1024, 512, 0, stream>>>(
                inH, inL, w1h, w1l, b1, h_hi, h_lo, nullptr, H, D, B / 256, H / 128);
        } else {
            // Tier B: reg-staged A (r10 structure + swizzle fix).
            bgemm1_8p<<<1024, 512, 0, stream>>>(inp, w1h, w1l, b1, h_hi, h_lo);
        }
        // GEMM2 (both tiers): gload-staged pipeline on pre-split h and W2.
        bgemm_glds<0><<<256, 512, 0, stream>>>(
            h_hi, h_lo, w2h, w2l, b2, nullptr, nullptr, l32, F, H, B / 256, F / 128);

        margin_topk32<<<B / 4, 256, 0, stream>>>(l32, out, F, kp, risky, cnt, MAXR);
        repair_r1<<<dim3(4, MAXR / 4), 256, 0, stream>>>(
            inp, W1, b1, h64, risky, cnt, MAXR);
        repair_r2<<<dim3(1, MAXR / 4), 256, 0, stream>>>(
            h64, W2, b2, L64, cnt, MAXR);
        topk64_kernel<<<MAXR / 4, 256, 0, stream>>>(L64, out, F, kp, risky, cnt, MAXR);
    } else {
        // Fallback: full-fp64 chunked pipeline (verified r3).
        int Hc = H, Bc = 0;
        for (;;) {
            size_t perRow = (size_t)F * 8 + (size_t)Hc * 8;
            Bc = (int)((ws_size / perRow) / BM) * BM;
            if (Bc >= BM || Hc <= BM) break;
            Hc >>= 1;
        }
        if (Bc < BM) Bc = BM;
        if (Bc > B)  Bc = B;
        double* L   = (double*)d_ws;
        double* h64 = L + (size_t)Bc * F;

        for (int b0 = 0; b0 < B; b0 += Bc) {
            int bc = (B - b0 < Bc) ? (B - b0) : Bc;
            for (int h0 = 0; h0 < H; h0 += Hc) {
                int hc = (H - h0 < Hc) ? (H - h0) : Hc;
                gemm64<float, 0><<<dim3(bc / BM, hc / BN), 256, 0, stream>>>(
                    inp + (size_t)b0 * D, D, W1 + (size_t)h0 * D, D, b1 + h0,
                    h64, hc, D);
                if (h0 == 0)
                    gemm64<double, 1><<<dim3(bc / BM, F / BN), 256, 0, stream>>>(
                        h64, hc, W2 + h0, H, b2, L, F, hc);
                else
                    gemm64<double, 2><<<dim3(bc / BM, F / BN), 256, 0, stream>>>(
                        h64, hc, W2 + h0, H, b2, L, F, hc);
            }
            topk64_kernel<<<bc / 4, 256, 0, stream>>>(
                L, out + (size_t)b0 * F, F, kp, nullptr, nullptr, 0);
        }
    }
}

// Round 13
// 1237.429 us; speedup vs baseline: 1.3813x; 1.1332x over previous
//
#include <hip/hip_runtime.h>
#include <math.h>
#include <type_traits>

// Fused MLP head with BINARY output (per-row top-k gate + 0.2 hardlim).
// Verified architecture: bf16-split(3-product) MFMA fast pass -> logit-margin
// flags (TAU=1e-4) -> streaming fp64 repair of flagged rows -> exact gate.
// r12: GEMM1 tile 256x128 -> 256x256 (staged bytes/FLOP -33%, MFMA/barrier x2;
//      staging BW was the binding resource: 857 cyc L2 + 690 cyc LDS vs 466
//      cyc MFMA per tile). 2x64KB LDS bufs, simple 2-phase sync, r11-proven
//      gload/swizzle formulas verbatim; K-order bit-identical to r11.
//      repair_r1 -> 8 rows/block (halves W1 re-streams); init folded into
//      split_kernel. Tier B dropped (r11 proved ws >= needA).

#define BM 128
#define BN 128
#define BK 16      // fp64 fallback K-step

#define TAU   1.0e-4f
#define L02F -1.3862943611198906f   /* ln(0.2/0.8) */

typedef __attribute__((ext_vector_type(8))) short  bf16x8;
typedef __attribute__((ext_vector_type(8))) ushort u16x8;
typedef __attribute__((ext_vector_type(4))) float  f32x4;

__device__ inline ushort bfhi(float f)   { return (ushort)(__float_as_uint(f) >> 16); }
__device__ inline float  bfhif(float f)  { return __uint_as_float(__float_as_uint(f) & 0xFFFF0000u); }

__device__ inline void gload_lds16(const void* g, void* l) {
    __builtin_amdgcn_global_load_lds(
        (const __attribute__((address_space(1))) unsigned int*)g,
        (__attribute__((address_space(3))) unsigned int*)l, 16, 0, 0);
}

// ---------------- fp32 -> (hi, lo) bf16 split (+ optional cnt zero) --------
__global__ __launch_bounds__(256) void split_kernel(
    const float* __restrict__ src, ushort* __restrict__ hi,
    ushort* __restrict__ lo, size_t n4, int* cnt)
{
    if (cnt && blockIdx.x == 0 && threadIdx.x == 0) *cnt = 0;
    size_t i = (size_t)blockIdx.x * 256 + threadIdx.x;
    size_t stride = (size_t)gridDim.x * 256;
    for (; i < n4; i += stride) {
        float4 v = ((const float4*)src)[i];
        ushort4 h, l;
        h.x = bfhi(v.x); l.x = bfhi(v.x - bfhif(v.x));
        h.y = bfhi(v.y); l.y = bfhi(v.y - bfhif(v.y));
        h.z = bfhi(v.z); l.z = bfhi(v.z - bfhif(v.z));
        h.w = bfhi(v.w); l.w = bfhi(v.w - bfhif(v.w));
        ((ushort4*)hi)[i] = h;
        ((ushort4*)lo)[i] = l;
    }
}

// ---------------- GEMM1: 256x256 tile, 2x64KB bufs, gload-staged -----------
// C(split) = relu(inp @ W1^T + b1). Fixed 16384x2048x4096, BK=32.
// 512 thr (8 waves, 4m x 2n; wave tile 64x128).
__global__ __launch_bounds__(512, 2) void bgemm1_256(
    const ushort* __restrict__ aH, const ushort* __restrict__ aL,
    const ushort* __restrict__ wH, const ushort* __restrict__ wL,
    const float* __restrict__ b1,
    ushort* __restrict__ Chi, ushort* __restrict__ Clo)
{
    __shared__ ushort lds[65536];          // 2 bufs x 32768 ush (64 KB each)
    const int t    = threadIdx.x;
    const int lane = t & 63;
    const int wave = t >> 6;
    const int wr   = wave >> 1;            // 0..3 (64-row block)
    const int wc   = wave & 1;             // 0..1 (128-col block)
    const int l15  = lane & 15;
    const int l4   = lane >> 4;

    // XCD: contiguous bm per XCD, bn fastest. 512 blocks (64 bm x 8 bn).
    const int bid = blockIdx.x;
    const int xcd = bid & 7;
    const int j   = bid >> 3;              // 0..63
    const int bm  = xcd * 8 + (j >> 3);    // 0..63
    const int bn  = j & 7;                 // 0..7

    // staging: per wave 8 gloads, rows wave*32..+31 of each region
    const int cq = lane & 3;
    const int r0 = wave * 32 + (lane >> 2);
    const int r1 = r0 + 16;
    const size_t sw0 = (size_t)((cq ^ ((r0 >> 1) & 3)) * 8);
    const size_t sw1 = (size_t)((cq ^ ((r1 >> 1) & 3)) * 8);
    const size_t gA0 = (size_t)(bm * 256 + r0) * 4096 + sw0;
    const size_t gA1 = (size_t)(bm * 256 + r1) * 4096 + sw1;
    const size_t gB0 = (size_t)(bn * 256 + r0) * 4096 + sw0;
    const size_t gB1 = (size_t)(bn * 256 + r1) * 4096 + sw1;

    f32x4 acc[4][8];
    #pragma unroll
    for (int mi = 0; mi < 4; ++mi)
        #pragma unroll
        for (int ni = 0; ni < 8; ++ni)
            acc[mi][ni] = (f32x4){0.f, 0.f, 0.f, 0.f};

    auto stage = [&](int b, int kt) {
        const size_t ko = (size_t)kt * 32;
        ushort* L0 = &lds[b * 32768];
        gload_lds16(aH + gA0 + ko, L0 + wave * 1024);
        gload_lds16(aH + gA1 + ko, L0 + wave * 1024 + 512);
        gload_lds16(aL + gA0 + ko, L0 + 8192 + wave * 1024);
        gload_lds16(aL + gA1 + ko, L0 + 8192 + wave * 1024 + 512);
        gload_lds16(wH + gB0 + ko, L0 + 16384 + wave * 1024);
        gload_lds16(wH + gB1 + ko, L0 + 16384 + wave * 1024 + 512);
        gload_lds16(wL + gB0 + ko, L0 + 24576 + wave * 1024);
        gload_lds16(wL + gB1 + ko, L0 + 24576 + wave * 1024 + 512);
    };
    auto compute = [&](int b) {
        const ushort* L0 = &lds[b * 32768];
        bf16x8 ah[4], al[4];
        #pragma unroll
        for (int mi = 0; mi < 4; ++mi) {
            int row = wr * 64 + mi * 16 + l15;
            int o = row * 32 + ((l4 ^ ((row >> 1) & 3)) << 3);
            ah[mi] = *(const bf16x8*)&L0[o];
            al[mi] = *(const bf16x8*)&L0[8192 + o];
        }
        #pragma unroll
        for (int h = 0; h < 2; ++h) {
            bf16x8 bh[4], bl[4];
            #pragma unroll
            for (int q = 0; q < 4; ++q) {
                int row = wc * 128 + (h * 4 + q) * 16 + l15;
                int o = row * 32 + ((l4 ^ ((row >> 1) & 3)) << 3);
                bh[q] = *(const bf16x8*)&L0[16384 + o];
                bl[q] = *(const bf16x8*)&L0[24576 + o];
            }
            __builtin_amdgcn_s_setprio(1);
            #pragma unroll
            for (int mi = 0; mi < 4; ++mi)
                #pragma unroll
                for (int q = 0; q < 4; ++q) {
                    acc[mi][h * 4 + q] = __builtin_amdgcn_mfma_f32_16x16x32_bf16(ah[mi], bh[q], acc[mi][h * 4 + q], 0, 0, 0);
                    acc[mi][h * 4 + q] = __builtin_amdgcn_mfma_f32_16x16x32_bf16(ah[mi], bl[q], acc[mi][h * 4 + q], 0, 0, 0);
                    acc[mi][h * 4 + q] = __builtin_amdgcn_mfma_f32_16x16x32_bf16(al[mi], bh[q], acc[mi][h * 4 + q], 0, 0, 0);
                }
            __builtin_amdgcn_s_setprio(0);
        }
    };

    // prologue
    stage(0, 0);
    asm volatile("s_waitcnt vmcnt(0)");
    __builtin_amdgcn_s_barrier();

    const int nt = 128;  // 4096/32
    for (int kt = 0; kt < nt - 1; ++kt) {
        stage((kt + 1) & 1, kt + 1);       // issue first: latency under MFMA
        __builtin_amdgcn_sched_barrier(0);
        compute(kt & 1);
        asm volatile("s_waitcnt vmcnt(0)");
        asm volatile("s_waitcnt lgkmcnt(0)\n\ts_barrier" ::: "memory");
    }
    compute((nt - 1) & 1);

    // epilogue: relu + split-store (verified r5 C/D mapping)
    #pragma unroll
    for (int ni = 0; ni < 8; ++ni) {
        int col = bn * 256 + wc * 128 + ni * 16 + l15;
        float bv = b1[col];
        #pragma unroll
        for (int mi = 0; mi < 4; ++mi) {
            int rowb = bm * 256 + wr * 64 + mi * 16 + l4 * 4;
            #pragma unroll
            for (int r = 0; r < 4; ++r) {
                float v = fmaxf(acc[mi][ni][r] + bv, 0.0f);
                size_t idx = (size_t)(rowb + r) * 2048 + col;
                Chi[idx] = bfhi(v);
                Clo[idx] = bfhi(v - bfhif(v));
            }
        }
    }
}

// ---------------- bgemm_glds (r11-verified): GEMM2 path --------------------
// Tile 256x128, BK=32, 512 thr, 3 LDS bufs of 48 KiB, counted vmcnt.
template<int OUT_SPLIT>
__global__ __launch_bounds__(512, 2) void bgemm_glds(
    const ushort* __restrict__ aH, const ushort* __restrict__ aL,
    const ushort* __restrict__ wH, const ushort* __restrict__ wL,
    const float* __restrict__ bias,
    ushort* __restrict__ Chi, ushort* __restrict__ Clo,
    float* __restrict__ C32,
    int N, int K, int nbm, int nbn)
{
    __shared__ ushort lds[73728];
    const int t    = threadIdx.x;
    const int lane = t & 63;
    const int wave = t >> 6;
    const int wr   = wave >> 1;
    const int wc   = wave & 1;
    const int l15  = lane & 15;
    const int l4   = lane >> 4;

    const int bid = blockIdx.x;
    const int xcd = bid & 7;
    const int j   = bid >> 3;
    const int bm  = xcd * (nbm >> 3) + j / nbn;
    const int bn  = j % nbn;

    const int c   = lane & 3;
    const int rA0 = (wave * 2 + 0) * 16 + (lane >> 2);
    const int rA1 = (wave * 2 + 1) * 16 + (lane >> 2);
    const int rB  = wave * 16 + (lane >> 2);
    const size_t offA0 = (size_t)(bm * 256 + rA0) * K + (size_t)((c ^ ((rA0 >> 1) & 3)) * 8);
    const size_t offA1 = (size_t)(bm * 256 + rA1) * K + (size_t)((c ^ ((rA1 >> 1) & 3)) * 8);
    const size_t offB  = (size_t)(bn * 128 + rB ) * K + (size_t)((c ^ ((rB  >> 1) & 3)) * 8);
    const ushort* sAh0 = aH + offA0; const ushort* sAl0 = aL + offA0;
    const ushort* sAh1 = aH + offA1; const ushort* sAl1 = aL + offA1;
    const ushort* sBh  = wH + offB;  const ushort* sBl  = wL + offB;

    f32x4 acc[4][4];
    #pragma unroll
    for (int mi = 0; mi < 4; ++mi)
        #pragma unroll
        for (int ni = 0; ni < 4; ++ni)
            acc[mi][ni] = (f32x4){0.f, 0.f, 0.f, 0.f};

    auto stage = [&](int b, int kt) {
        const size_t ko = (size_t)kt * 32;
        ushort* L0 = &lds[b * 24576];
        gload_lds16(sAh0 + ko, L0 + (wave * 2 + 0) * 512);
        gload_lds16(sAh1 + ko, L0 + (wave * 2 + 1) * 512);
        gload_lds16(sAl0 + ko, L0 + 8192 + (wave * 2 + 0) * 512);
        gload_lds16(sAl1 + ko, L0 + 8192 + (wave * 2 + 1) * 512);
        gload_lds16(sBh + ko,  L0 + 16384 + wave * 512);
        gload_lds16(sBl + ko,  L0 + 20480 + wave * 512);
    };
    auto frag_read = [&](int b, bf16x8 ah[4], bf16x8 al[4], bf16x8 bh[4], bf16x8 bl[4]) {
        const ushort* L0 = &lds[b * 24576];
        #pragma unroll
        for (int mi = 0; mi < 4; ++mi) {
            int row = wr * 64 + mi * 16 + l15;
            int o = row * 32 + ((l4 ^ ((row >> 1) & 3)) << 3);
            ah[mi] = *(const bf16x8*)&L0[o];
            al[mi] = *(const bf16x8*)&L0[8192 + o];
        }
        #pragma unroll
        for (int ni = 0; ni < 4; ++ni) {
            int row = wc * 64 + ni * 16 + l15;
            int o = row * 32 + ((l4 ^ ((row >> 1) & 3)) << 3);
            bh[ni] = *(const bf16x8*)&L0[16384 + o];
            bl[ni] = *(const bf16x8*)&L0[20480 + o];
        }
    };
    auto do_mfma = [&](bf16x8 ah[4], bf16x8 al[4], bf16x8 bh[4], bf16x8 bl[4]) {
        __builtin_amdgcn_s_setprio(1);
        #pragma unroll
        for (int mi = 0; mi < 4; ++mi)
            #pragma unroll
            for (int ni = 0; ni < 4; ++ni) {
                acc[mi][ni] = __builtin_amdgcn_mfma_f32_16x16x32_bf16(ah[mi], bh[ni], acc[mi][ni], 0, 0, 0);
                acc[mi][ni] = __builtin_amdgcn_mfma_f32_16x16x32_bf16(ah[mi], bl[ni], acc[mi][ni], 0, 0, 0);
                acc[mi][ni] = __builtin_amdgcn_mfma_f32_16x16x32_bf16(al[mi], bh[ni], acc[mi][ni], 0, 0, 0);
            }
        __builtin_amdgcn_s_setprio(0);
    };

    stage(0, 0);
    stage(1, 1);
    asm volatile("s_waitcnt vmcnt(6)");
    __builtin_amdgcn_s_barrier();

    const int nt = K / 32;
    bf16x8 ah[4], al[4], bh[4], bl[4];

    for (int kt = 0; kt < nt - 2; ++kt) {
        frag_read(kt % 3, ah, al, bh, bl);
        stage((kt + 2) % 3, kt + 2);
        __builtin_amdgcn_sched_barrier(0);
        do_mfma(ah, al, bh, bl);
        asm volatile("s_waitcnt vmcnt(6)");
        asm volatile("s_waitcnt lgkmcnt(0)\n\ts_barrier" ::: "memory");
    }
    {
        frag_read((nt - 2) % 3, ah, al, bh, bl);
        do_mfma(ah, al, bh, bl);
        asm volatile("s_waitcnt vmcnt(0)");
        asm volatile("s_waitcnt lgkmcnt(0)\n\ts_barrier" ::: "memory");
    }
    {
        frag_read((nt - 1) % 3, ah, al, bh, bl);
        do_mfma(ah, al, bh, bl);
    }

    #pragma unroll
    for (int ni = 0; ni < 4; ++ni) {
        int col = bn * 128 + wc * 64 + ni * 16 + l15;
        float bv = bias[col];
        #pragma unroll
        for (int mi = 0; mi < 4; ++mi) {
            int rowb = bm * 256 + wr * 64 + mi * 16 + l4 * 4;
            #pragma unroll
            for (int r = 0; r < 4; ++r) {
                float v = acc[mi][ni][r] + bv;
                size_t idx = (size_t)(rowb + r) * N + col;
                if (OUT_SPLIT) {
                    v = fmaxf(v, 0.0f);
                    Chi[idx] = bfhi(v);
                    Clo[idx] = bfhi(v - bfhif(v));
                } else {
                    C32[idx] = v;
                }
            }
        }
    }
}

// ---------------- streaming fp64 repair, stage 1 (8 rows/block) ------------
__global__ __launch_bounds__(256) void repair_r1(
    const float* __restrict__ inp,
    const float* __restrict__ W1, const float* __restrict__ b1,
    double* __restrict__ h64,
    const int* __restrict__ risky, const int* __restrict__ cnt, int maxr)
{
    int c = *cnt; if (c > maxr) c = maxr;
    const int by = blockIdx.y;
    if (by * 8 >= c) return;
    __shared__ float Xs[8][4096];          // 128 KB
    const int t = threadIdx.x;

    int ridx[8];
    #pragma unroll
    for (int r = 0; r < 8; ++r) {
        int slot = by * 8 + r;
        ridx[r] = risky[slot < c ? slot : (c - 1)];
    }
    #pragma unroll
    for (int i = 0; i < 32; ++i) {
        int lin = t + i * 256;             // 0..8191 float4 slots
        int r = lin >> 10, q = lin & 1023;
        *(float4*)&Xs[r][q * 4] = *(const float4*)(inp + (size_t)ridx[r] * 4096 + q * 4);
    }
    __syncthreads();

    const int n0 = blockIdx.x * 256 + t;   // 8 x-blocks x 256 = 2048
    const float* w0 = W1 + (size_t)n0 * 4096;
    double acc[8] = {};

    for (int k = 0; k < 4096; k += 4) {
        float4 a0 = *(const float4*)(w0 + k);
        float xr[8][4];
        #pragma unroll
        for (int r = 0; r < 8; ++r)
            *(float4*)&xr[r][0] = *(const float4*)&Xs[r][k];
        const float* ap0 = &a0.x;
        #pragma unroll
        for (int j = 0; j < 4; ++j) {
            double wd0 = (double)ap0[j];
            #pragma unroll
            for (int r = 0; r < 8; ++r)
                acc[r] = fma(wd0, (double)xr[r][j], acc[r]);
        }
    }

    double bv0 = (double)b1[n0];
    #pragma unroll
    for (int r = 0; r < 8; ++r) {
        int slot = by * 8 + r;
        if (slot < c)
            h64[(size_t)slot * 2048 + n0] = fmax(acc[r] + bv0, 0.0);
    }
}

// ---------------- streaming fp64 repair, stage 2 (r7-verified) -------------
__global__ __launch_bounds__(256) void repair_r2(
    const double* __restrict__ h64,
    const float* __restrict__ W2, const float* __restrict__ b2,
    double* __restrict__ L64,
    const int* __restrict__ cnt, int maxr)
{
    int c = *cnt; if (c > maxr) c = maxr;
    const int by = blockIdx.y;
    if (by * 4 >= c) return;
    __shared__ double Xs[4][2048];
    const int t = threadIdx.x;

    #pragma unroll
    for (int i = 0; i < 16; ++i) {
        int lin = t + i * 256;
        int r = lin >> 10, q = lin & 1023;
        int slot = by * 4 + r; if (slot >= c) slot = c - 1;
        *(double2*)&Xs[r][q * 2] = *(const double2*)(h64 + (size_t)slot * 2048 + q * 2);
    }
    __syncthreads();

    const int n0 = t;
    const int n1 = t + 256;
    const float* w0 = W2 + (size_t)n0 * 2048;
    const float* w1 = W2 + (size_t)n1 * 2048;
    double acc[2][4] = {};

    for (int k = 0; k < 2048; k += 4) {
        float4 a0 = *(const float4*)(w0 + k);
        float4 a1 = *(const float4*)(w1 + k);
        double xr[4][4];
        #pragma unroll
        for (int r = 0; r < 4; ++r) {
            *(double2*)&xr[r][0] = *(const double2*)&Xs[r][k];
            *(double2*)&xr[r][2] = *(const double2*)&Xs[r][k + 2];
        }
        const float* ap0 = &a0.x;
        const float* ap1 = &a1.x;
        #pragma unroll
        for (int j = 0; j < 4; ++j) {
            double wd0 = (double)ap0[j];
            double wd1 = (double)ap1[j];
            #pragma unroll
            for (int r = 0; r < 4; ++r) {
                acc[0][r] = fma(wd0, xr[r][j], acc[0][r]);
                acc[1][r] = fma(wd1, xr[r][j], acc[1][r]);
            }
        }
    }

    double bv0 = (double)b2[n0], bv1 = (double)b2[n1];
    #pragma unroll
    for (int r = 0; r < 4; ++r) {
        int slot = by * 4 + r;
        if (slot < c) {
            L64[(size_t)slot * 512 + n0] = acc[0][r] + bv0;
            L64[(size_t)slot * 512 + n1] = acc[1][r] + bv1;
        }
    }
}

// ---------------- fp64 GEMM (r3-verified; fallback tier only) --------------
template<typename TA, int MODE>
__global__ __launch_bounds__(256, 1) void gemm64(
    const TA* __restrict__ A, int lda,
    const float* __restrict__ W, int ldw,
    const float* __restrict__ bias,
    double* __restrict__ out64, int N, int K)
{
    __shared__ double As[BK][BM + 2];
    __shared__ double Bs[BK][BN + 2];
    const int t  = threadIdx.x;
    const int tm = t >> 4;
    const int tn = t & 15;
    const size_t bm = blockIdx.x;
    const size_t bn = blockIdx.y;
    const TA*    Ab = A + bm * BM * (size_t)lda;
    const float* Wb = W + bn * BN * (size_t)ldw;

    double acc[8][8] = {};

    for (int k0 = 0; k0 < K; k0 += BK) {
        #pragma unroll
        for (int i = 0; i < 2; ++i) {
            int f   = t + i * 256;
            int row = f >> 2;
            int kc  = (f & 3) << 2;
            if constexpr (std::is_same<TA, double>::value) {
                double2 v0 = *(const double2*)(Ab + (size_t)row * lda + k0 + kc);
                double2 v1 = *(const double2*)(Ab + (size_t)row * lda + k0 + kc + 2);
                As[kc + 0][row] = v0.x; As[kc + 1][row] = v0.y;
                As[kc + 2][row] = v1.x; As[kc + 3][row] = v1.y;
            } else {
                float4 va = *(const float4*)(Ab + (size_t)row * lda + k0 + kc);
                As[kc + 0][row] = (double)va.x; As[kc + 1][row] = (double)va.y;
                As[kc + 2][row] = (double)va.z; As[kc + 3][row] = (double)va.w;
            }
            float4 vb = *(const float4*)(Wb + (size_t)row * ldw + k0 + kc);
            Bs[kc + 0][row] = (double)vb.x; Bs[kc + 1][row] = (double)vb.y;
            Bs[kc + 2][row] = (double)vb.z; Bs[kc + 3][row] = (double)vb.w;
        }
        __syncthreads();
        #pragma unroll
        for (int k = 0; k < BK; ++k) {
            double a[8], b[8];
            #pragma unroll
            for (int i = 0; i < 4; ++i) {
                *(double2*)&a[i * 2] = *(const double2*)&As[k][tm * 8 + i * 2];
                *(double2*)&b[i * 2] = *(const double2*)&Bs[k][tn * 8 + i * 2];
            }
            #pragma unroll
            for (int i = 0; i < 8; ++i)
                #pragma unroll
                for (int j = 0; j < 8; ++j)
                    acc[i][j] = fma(a[i], b[j], acc[i][j]);
        }
        __syncthreads();
    }

    double bv[8];
    if (MODE != 2) {
        #pragma unroll
        for (int j = 0; j < 8; ++j) bv[j] = (double)bias[bn * BN + tn * 8 + j];
    }

    #pragma unroll
    for (int i = 0; i < 8; ++i) {
        size_t row  = bm * BM + (size_t)tm * 8 + i;
        size_t base = row * (size_t)N + bn * BN + tn * 8;
        #pragma unroll
        for (int j = 0; j < 8; ++j) {
            double v = acc[i][j];
            if (MODE == 0) out64[base + j] = fmax(v + bv[j], 0.0);
            if (MODE == 1) out64[base + j] = v + bv[j];
            if (MODE == 2) out64[base + j] += v;
        }
    }
}

// ---------------- fp32 top-k + margin flag + gate (in-place safe) ----------
__global__ __launch_bounds__(256) void margin_topk32(
    const float* L, float* O, int ncols,
    const int* __restrict__ kp, int* __restrict__ risky, int* __restrict__ cnt,
    int maxr)
{
    const int wave = threadIdx.x >> 6;
    const int lane = threadIdx.x & 63;
    const int k = *kp;
    const size_t row = (size_t)blockIdx.x * 4 + wave;
    const float* Lr = L + row * (size_t)ncols;

    float v[8];
    *(float4*)&v[0] = *(const float4*)(Lr + lane * 8);
    *(float4*)&v[4] = *(const float4*)(Lr + lane * 8 + 4);
    float w[8];
    #pragma unroll
    for (int j = 0; j < 8; ++j) w[j] = v[j];

    float kth = -3.0e38f, minD = 3.0e38f;
    for (int it = 0; it < k; ++it) {
        float mv = w[0]; int mj = 0;
        #pragma unroll
        for (int j = 1; j < 8; ++j)
            if (w[j] > mv) { mv = w[j]; mj = j; }
        int mi = lane * 8 + mj;
        #pragma unroll
        for (int off = 32; off; off >>= 1) {
            float ov = __shfl_xor(mv, off);
            int   oi = __shfl_xor(mi, off);
            if (ov > mv || (ov == mv && oi < mi)) { mv = ov; mi = oi; }
        }
        kth = mv;
        minD = fminf(minD, fabsf(mv - L02F));
        if ((mi >> 3) == lane) w[mi & 7] = -3.0e38f;
    }
    float nv = w[0];
    #pragma unroll
    for (int j = 1; j < 8; ++j) nv = fmaxf(nv, w[j]);
    #pragma unroll
    for (int off = 32; off; off >>= 1) nv = fmaxf(nv, __shfl_xor(nv, off));

    bool risk = ((kth - nv) < 2.0f * TAU) || (minD < TAU);
    if (risk && lane == 0) {
        int p = atomicAdd(cnt, 1);
        if (p < maxr) risky[p] = (int)row;
    }

    float o[8];
    #pragma unroll
    for (int j = 0; j < 8; ++j)
        o[j] = (v[j] >= kth && v[j] > L02F) ? 1.0f : 0.0f;
    float* Op = O + row * (size_t)ncols + lane * 8;
    *(float4*)&Op[0] = *(const float4*)&o[0];
    *(float4*)&Op[4] = *(const float4*)&o[4];
}

// ---------------- fp64 top-k (r3-verified), direct or gathered -------------
__global__ __launch_bounds__(256) void topk64_kernel(
    const double* __restrict__ L, float* __restrict__ O, int ncols,
    const int* __restrict__ kp,
    const int* __restrict__ risky, const int* __restrict__ cnt, int maxr)
{
    const int wave = threadIdx.x >> 6;
    const int lane = threadIdx.x & 63;
    const int k = *kp;
    size_t pos = (size_t)blockIdx.x * 4 + wave;
    size_t row = pos;
    if (cnt) {
        int c = *cnt; if (c > maxr) c = maxr;
        if ((int)pos >= c) return;
        row = (size_t)risky[pos];
    }
    const double* Lr = L + pos * (size_t)ncols;

    double v[8];
    #pragma unroll
    for (int j = 0; j < 8; ++j) {
        double l = Lr[lane * 8 + j];
        v[j] = 1.0 / (1.0 + exp(-l));
    }
    double w[8];
    #pragma unroll
    for (int j = 0; j < 8; ++j) w[j] = v[j];

    double kth = -1.0e300;
    for (int it = 0; it < k; ++it) {
        double mv = w[0]; int mj = 0;
        #pragma unroll
        for (int j = 1; j < 8; ++j)
            if (w[j] > mv) { mv = w[j]; mj = j; }
        int mi = lane * 8 + mj;
        #pragma unroll
        for (int off = 32; off; off >>= 1) {
            double ov = __shfl_xor(mv, off);
            int    oi = __shfl_xor(mi, off);
            if (ov > mv || (ov == mv && oi < mi)) { mv = ov; mi = oi; }
        }
        kth = mv;
        if ((mi >> 3) == lane) w[mi & 7] = -1.0e300;
    }

    float o[8];
    #pragma unroll
    for (int j = 0; j < 8; ++j)
        o[j] = (v[j] >= kth && v[j] > 0.2) ? 1.0f : 0.0f;
    float* Op = O + row * (size_t)ncols + lane * 8;
    *(float4*)&Op[0] = *(const float4*)&o[0];
    *(float4*)&Op[4] = *(const float4*)&o[4];
}

extern "C" void kernel_launch(void* const* d_in, const int* in_sizes, int n_in,
                              void* d_out, int out_size, void* d_ws, size_t ws_size,
                              hipStream_t stream) {
    const float* inp = (const float*)d_in[0];
    const float* W1  = (const float*)d_in[1];
    const float* b1  = (const float*)d_in[2];
    const float* W2  = (const float*)d_in[3];
    const float* b2  = (const float*)d_in[4];
    const int*   kp  = (const int*)d_in[5];

    const int H = in_sizes[2];              // 2048
    const int F = in_sizes[4];              // 512
    const int D = in_sizes[1] / H;          // 4096
    const int B = in_sizes[0] / D;          // 16384
    float* out = (float*)d_out;

    const int MAXR = 8192;
    const size_t szHpair = (size_t)B * H * 4;        // 128 MiB
    const size_t szW1p   = (size_t)H * D * 4;        // 32 MiB
    const size_t szW2p   = (size_t)F * H * 4;        // 4 MiB
    const size_t szInpP  = (size_t)B * D * 4;        // 256 MiB
    const size_t needMain = szHpair + szW1p + szW2p + (size_t)MAXR * 4 + 256;
    const size_t needA    = needMain + szInpP;
    const bool shapeOK = (D == 4096 && H == 2048 && F == 512 && B == 16384);

    if (shapeOK && ws_size >= needA) {
        ushort* h_hi  = (ushort*)d_ws;
        ushort* h_lo  = h_hi + (size_t)B * H;
        ushort* w1h   = (ushort*)((char*)d_ws + szHpair);
        ushort* w1l   = w1h + (size_t)H * D;
        ushort* w2h   = (ushort*)((char*)d_ws + szHpair + szW1p);
        ushort* w2l   = w2h + (size_t)F * H;
        int*    risky = (int*)((char*)d_ws + szHpair + szW1p + szW2p);
        int*    cnt   = risky + MAXR;
        ushort* inH   = (ushort*)((char*)d_ws + needMain);
        ushort* inL   = inH + (size_t)B * D;
        double* h64   = (double*)d_ws;                        // repair: aliases h pair
        double* L64   = (double*)((char*)d_ws + szHpair);     // repair: aliases W1 pair
        float*  l32   = out;                                  // logits in d_out

        split_kernel<<<2048, 256, 0, stream>>>(W1, w1h, w1l, (size_t)H * D / 4, cnt);
        split_kernel<<<512, 256, 0, stream>>>(W2, w2h, w2l, (size_t)F * H / 4, nullptr);
        split_kernel<<<4096, 256, 0, stream>>>(inp, inH, inL, (size_t)B * D / 4, nullptr);
        bgemm1_256<<<512, 512, 0, stream>>>(inH, inL, w1h, w1l, b1, h_hi, h_lo);
        bgemm_glds<0><<<256, 512, 0, stream>>>(
            h_hi, h_lo, w2h, w2l, b2, nullptr, nullptr, l32, F, H, B / 256, F / 128);
        margin_topk32<<<B / 4, 256, 0, stream>>>(l32, out, F, kp, risky, cnt, MAXR);
        repair_r1<<<dim3(8, MAXR / 8), 256, 0, stream>>>(
            inp, W1, b1, h64, risky, cnt, MAXR);
        repair_r2<<<dim3(1, MAXR / 4), 256, 0, stream>>>(
            h64, W2, b2, L64, cnt, MAXR);
        topk64_kernel<<<MAXR / 4, 256, 0, stream>>>(L64, out, F, kp, risky, cnt, MAXR);
    } else {
        // Fallback: full-fp64 chunked pipeline (verified r3).
        int Hc = H, Bc = 0;
        for (;;) {
            size_t perRow = (size_t)F * 8 + (size_t)Hc * 8;
            Bc = (int)((ws_size / perRow) / BM) * BM;
            if (Bc >= BM || Hc <= BM) break;
            Hc >>= 1;
        }
        if (Bc < BM) Bc = BM;
        if (Bc > B)  Bc = B;
        double* L   = (double*)d_ws;
        double* h64 = L + (size_t)Bc * F;

        for (int b0 = 0; b0 < B; b0 += Bc) {
            int bc = (B - b0 < Bc) ? (B - b0) : Bc;
            for (int h0 = 0; h0 < H; h0 += Hc) {
                int hc = (H - h0 < Hc) ? (H - h0) : Hc;
                gemm64<float, 0><<<dim3(bc / BM, hc / BN), 256, 0, stream>>>(
                    inp + (size_t)b0 * D, D, W1 + (size_t)h0 * D, D, b1 + h0,
                    h64, hc, D);
                if (h0 == 0)
                    gemm64<double, 1><<<dim3(bc / BM, F / BN), 256, 0, stream>>>(
                        h64, hc, W2 + h0, H, b2, L, F, hc);
                else
                    gemm64<double, 2><<<dim3(bc / BM, F / BN), 256, 0, stream>>>(
                        h64, hc, W2 + h0, H, b2, L, F, hc);
            }
            topk64_kernel<<<bc / 4, 256, 0, stream>>>(
                L, out + (size_t)b0 * F, F, kp, nullptr, nullptr, 0);
        }
    }
}